// Round 1
// baseline (67.119 us; speedup 1.0000x reference)
//
#include <hip/hip_runtime.h>
#include <math.h>

namespace {
constexpr int W = 256, H = 256, TILE = 16, NTX = 16, NT = 256, K = 256;
constexpr float FX = 200.0f, FY = 200.0f, NEARP = 0.3f, MAGIC = 1.2f;
constexpr float LP = 0.3f / (FX * FX);
constexpr float HALF_W = W * MAGIC / 2.0f / FX;   // 0.768
constexpr float HALF_H = H * MAGIC / 2.0f / FY;   // 0.768
constexpr float THDIAG = 0.05656854249492381f;    // 0.5*sqrt((TILE/FX)^2+(TILE/FY)^2)
constexpr int CAP = 2048;
}

struct Pre { float mx, my, z, a, b, c, radius; };

__device__ inline Pre preprocess(int g, const float* __restrict__ pos,
                                 const float* __restrict__ quat,
                                 const float* __restrict__ scl,
                                 const float* __restrict__ w2cr,
                                 const float* __restrict__ w2ct) {
  float p0 = pos[3*g+0], p1 = pos[3*g+1], p2 = pos[3*g+2];
  float qw = quat[4*g+0], qx = quat[4*g+1], qy = quat[4*g+2], qz = quat[4*g+3];
  float inv = 1.0f / sqrtf(qw*qw + qx*qx + qy*qy + qz*qz);
  qw *= inv; qx *= inv; qy *= inv; qz *= inv;
  float r00 = 1.f-2.f*(qy*qy+qz*qz), r01 = 2.f*(qx*qy-qw*qz), r02 = 2.f*(qx*qz+qw*qy);
  float r10 = 2.f*(qx*qy+qw*qz), r11 = 1.f-2.f*(qx*qx+qz*qz), r12 = 2.f*(qy*qz-qw*qx);
  float r20 = 2.f*(qx*qz-qw*qy), r21 = 2.f*(qy*qz+qw*qx), r22 = 1.f-2.f*(qx*qx+qy*qy);
  float e0 = expf(scl[3*g+0]); float s0 = e0*e0;
  float e1 = expf(scl[3*g+1]); float s1 = e1*e1;
  float e2 = expf(scl[3*g+2]); float s2 = e2*e2;
  // cov3d = R diag(s) R^T (symmetric)
  float C00 = r00*r00*s0 + r01*r01*s1 + r02*r02*s2;
  float C01 = r00*r10*s0 + r01*r11*s1 + r02*r12*s2;
  float C02 = r00*r20*s0 + r01*r21*s1 + r02*r22*s2;
  float C11 = r10*r10*s0 + r11*r11*s1 + r12*r12*s2;
  float C12 = r10*r20*s0 + r11*r21*s1 + r12*r22*s2;
  float C22 = r20*r20*s0 + r21*r21*s1 + r22*r22*s2;
  float w00=w2cr[0],w01=w2cr[1],w02=w2cr[2];
  float w10=w2cr[3],w11=w2cr[4],w12=w2cr[5];
  float w20=w2cr[6],w21=w2cr[7],w22=w2cr[8];
  float x = w00*p0 + w01*p1 + w02*p2 + w2ct[0];
  float y = w10*p0 + w11*p1 + w12*p2 + w2ct[1];
  float z = w20*p0 + w21*p1 + w22*p2 + w2ct[2];
  // cov_cam = Rw * cov3d * Rw^T
  float m00 = w00*C00 + w01*C01 + w02*C02;
  float m01 = w00*C01 + w01*C11 + w02*C12;
  float m02 = w00*C02 + w01*C12 + w02*C22;
  float m10 = w10*C00 + w11*C01 + w12*C02;
  float m11 = w10*C01 + w11*C11 + w12*C12;
  float m12 = w10*C02 + w11*C12 + w12*C22;
  float m20 = w20*C00 + w21*C01 + w22*C02;
  float m21 = w20*C01 + w21*C11 + w22*C12;
  float m22 = w20*C02 + w21*C12 + w22*C22;
  float v00 = m00*w00 + m01*w01 + m02*w02;
  float v01 = m00*w10 + m01*w11 + m02*w12;
  float v02 = m00*w20 + m01*w21 + m02*w22;
  float v10 = m10*w00 + m11*w01 + m12*w02;
  float v11 = m10*w10 + m11*w11 + m12*w12;
  float v12 = m10*w20 + m11*w21 + m12*w22;
  float v20 = m20*w00 + m21*w01 + m22*w02;
  float v21 = m20*w10 + m21*w11 + m22*w12;
  float v22 = m20*w20 + m21*w21 + m22*w22;
  float zc = fmaxf(z, 1e-6f);
  float iz = 1.0f / zc;
  float mx = x * iz, my = y * iz;
  float iz2 = iz * iz;
  float jx = -x * iz2, jy = -y * iz2;
  // A2 = J * cov_cam (2x3), J row0 = (iz,0,jx), row1 = (0,iz,jy)
  float a00 = iz*v00 + jx*v20, a01 = iz*v01 + jx*v21, a02 = iz*v02 + jx*v22;
  float a10 = iz*v10 + jy*v20, a11 = iz*v11 + jy*v21, a12 = iz*v12 + jy*v22;
  float A  = a00*iz + a02*jx + LP;   // cov2d[0][0] + LP
  float Bv = a01*iz + a02*jy;        // cov2d[0][1]
  float Cv = a11*iz + a12*jy + LP;   // cov2d[1][1] + LP
  float mid = 0.5f*(A + Cv);
  float hh  = 0.5f*(A - Cv);
  float disc = fmaxf(hh*hh + Bv*Bv, 0.0f);
  float smax = sqrtf(fmaxf(mid + sqrtf(disc), 1e-12f));
  bool infr = (z > NEARP) && (fabsf(mx) < HALF_W) && (fabsf(my) < HALF_H);
  Pre r;
  r.mx = mx; r.my = my; r.z = z; r.a = A; r.b = Bv; r.c = Cv;
  r.radius = infr ? (3.0f * smax + THDIAG) : -1.0f;
  return r;
}

template <bool WITH_PAY>
__device__ inline void bitonic_sort(unsigned long long* key,
                                    unsigned long long* pay, int M) {
  for (int k = 2; k <= M; k <<= 1) {
    for (int j = k >> 1; j > 0; j >>= 1) {
      __syncthreads();
      for (int i = (int)threadIdx.x; i < M; i += (int)blockDim.x) {
        int ixj = i ^ j;
        if (ixj > i) {
          unsigned long long a = key[i], b = key[ixj];
          bool up = ((i & k) == 0);
          bool swp = up ? (a > b) : (a < b);
          if (swp) {
            key[i] = b; key[ixj] = a;
            if constexpr (WITH_PAY) {
              unsigned long long t = pay[i]; pay[i] = pay[ixj]; pay[ixj] = t;
            }
          }
        }
      }
    }
  }
  __syncthreads();
}

__global__ __launch_bounds__(256)
void splat_tiles(const float* __restrict__ pos, const float* __restrict__ rgb,
                 const float* __restrict__ opac, const float* __restrict__ quat,
                 const float* __restrict__ scl, const float* __restrict__ w2cr,
                 const float* __restrict__ w2ct, float* __restrict__ out, int n) {
  __shared__ unsigned long long s_dkey[CAP];
  __shared__ unsigned long long s_zkey[CAP];
  __shared__ int s_cnt;
  __shared__ float s_mx[K], s_my[K], s_a[K], s_b[K], s_c[K], s_invdet[K];
  __shared__ float s_opa[K], s_cr[K], s_cg[K], s_cb[K];

  const int t  = blockIdx.x;
  const int tx = t % NTX;
  const int ty = t / NTX;
  const float cxc = (tx * TILE + TILE * 0.5f - W * 0.5f) / FX;
  const float cyc = (ty * TILE + TILE * 0.5f - H * 0.5f) / FY;

  if (threadIdx.x == 0) s_cnt = 0;
  __syncthreads();

  // Phase 1: collect valid candidates for this tile
  for (int g = (int)threadIdx.x; g < n; g += (int)blockDim.x) {
    Pre p = preprocess(g, pos, quat, scl, w2cr, w2ct);
    if (p.radius < 0.0f) continue;
    float ddx = cxc - p.mx, ddy = cyc - p.my;
    float dist = sqrtf(ddx * ddx + ddy * ddy);
    if (dist <= p.radius) {
      int slot = atomicAdd(&s_cnt, 1);
      if (slot < CAP) {
        s_dkey[slot] = ((unsigned long long)__float_as_uint(dist) << 32) | (unsigned int)g;
        s_zkey[slot] = ((unsigned long long)__float_as_uint(p.z)  << 32) | (unsigned int)g;
      }
    }
  }
  __syncthreads();
  int cnt = min(s_cnt, CAP);

  // Phase 2: selection + depth sort
  if (cnt > K) {
    // exact top-K by (dist, idx) ascending == jax.lax.top_k on -dist
    int M = 1; while (M < cnt) M <<= 1;
    for (int i = cnt + (int)threadIdx.x; i < M; i += (int)blockDim.x)
      s_dkey[i] = ~0ull;
    __syncthreads();
    bitonic_sort<true>(s_dkey, s_zkey, M);
    cnt = K;
    bitonic_sort<false>(s_zkey, nullptr, K);  // K == 256 is a power of two
  } else if (cnt > 0) {
    int M = 1; while (M < cnt) M <<= 1;
    for (int i = cnt + (int)threadIdx.x; i < M; i += (int)blockDim.x)
      s_zkey[i] = ~0ull;
    __syncthreads();
    bitonic_sort<false>(s_zkey, nullptr, M);
  }

  // Phase 3: preload blend params for the sorted list (cnt <= 256)
  for (int i = (int)threadIdx.x; i < cnt; i += (int)blockDim.x) {
    int g = (int)(s_zkey[i] & 0xffffffffu);
    Pre p = preprocess(g, pos, quat, scl, w2cr, w2ct);
    float det = fmaxf(p.a * p.c - p.b * p.b, 1e-12f);
    s_mx[i] = p.mx; s_my[i] = p.my;
    s_a[i] = p.a; s_b[i] = p.b; s_c[i] = p.c;
    s_invdet[i] = 1.0f / det;
    s_opa[i] = 1.0f / (1.0f + expf(-opac[g]));
    s_cr[i]  = 1.0f / (1.0f + expf(-rgb[3*g+0]));
    s_cg[i]  = 1.0f / (1.0f + expf(-rgb[3*g+1]));
    s_cb[i]  = 1.0f / (1.0f + expf(-rgb[3*g+2]));
  }
  __syncthreads();

  // Phase 4: per-pixel front-to-back blend
  const int pi = (int)threadIdx.x;
  const int prow = pi / TILE, pcol = pi % TILE;
  const float u = ((float)(tx * TILE + pcol) + 0.5f - W * 0.5f) / FX;
  const float v = ((float)(ty * TILE + prow) + 0.5f - H * 0.5f) / FY;
  float T = 1.0f, accr = 0.0f, accg = 0.0f, accb = 0.0f;
  for (int k2 = 0; k2 < cnt; ++k2) {
    float dx = u - s_mx[k2];
    float dy = v - s_my[k2];
    float maha = (s_c[k2]*dx*dx - 2.0f*s_b[k2]*dx*dy + s_a[k2]*dy*dy) * s_invdet[k2];
    float alpha = fminf(s_opa[k2] * expf(-0.5f * maha), 0.99f);
    float w = alpha * T;
    accr += w * s_cr[k2];
    accg += w * s_cg[k2];
    accb += w * s_cb[k2];
    T *= (1.0f - alpha);
    if (T < 1e-7f) break;  // residual contribution < 1e-7 << 1.8e-2 threshold
  }
  const int row = ty * TILE + prow;
  const int col = tx * TILE + pcol;
  const int o = (row * W + col) * 3;
  out[o+0] = fminf(fmaxf(accr, 0.0f), 1.0f);
  out[o+1] = fminf(fmaxf(accg, 0.0f), 1.0f);
  out[o+2] = fminf(fmaxf(accb, 0.0f), 1.0f);
}

extern "C" void kernel_launch(void* const* d_in, const int* in_sizes, int n_in,
                              void* d_out, int out_size, void* d_ws, size_t ws_size,
                              hipStream_t stream) {
  const float* pos  = (const float*)d_in[0];
  const float* rgb  = (const float*)d_in[1];
  const float* opac = (const float*)d_in[2];
  const float* quat = (const float*)d_in[3];
  const float* scl  = (const float*)d_in[4];
  const float* w2cr = (const float*)d_in[5];
  const float* w2ct = (const float*)d_in[6];
  float* out = (float*)d_out;
  const int n = in_sizes[0] / 3;
  splat_tiles<<<NT, 256, 0, stream>>>(pos, rgb, opac, quat, scl, w2cr, w2ct, out, n);
}

// Round 2
// 59.447 us; speedup vs baseline: 1.1290x; 1.1290x over previous
//
#include <hip/hip_runtime.h>
#include <math.h>

namespace {
constexpr int W = 256, H = 256, TILE = 16, NTX = 16, NT = 256, K = 256;
constexpr float FX = 200.0f, FY = 200.0f, NEARP = 0.3f, MAGIC = 1.2f;
constexpr float LP = 0.3f / (FX * FX);
constexpr float HALF_W = W * MAGIC / 2.0f / FX;   // 0.768
constexpr float HALF_H = H * MAGIC / 2.0f / FY;   // 0.768
constexpr float THDIAG = 0.05656854249492381f;    // 0.5*sqrt((TILE/FX)^2+(TILE/FY)^2)
constexpr int CAP = 2048;       // per-tile list capacity (global)
constexpr int N_PAD = 10240;

// ws SoA layout (floats)
constexpr int IDX_MX = 0, IDX_MY = 1, IDX_Z = 2, IDX_A = 3, IDX_B = 4,
              IDX_C = 5, IDX_IVD = 6, IDX_OPA = 7, IDX_CR = 8, IDX_CG = 9,
              IDX_CB = 10;
constexpr int N_ARR = 11;
constexpr size_t PM_BYTES   = (size_t)N_ARR * N_PAD * 4;          // 450560
constexpr size_t CNT_OFF    = PM_BYTES;                            // 256 ints
constexpr size_t LIST_OFF   = CNT_OFF + 1024;                      // 8B aligned
constexpr size_t WS_NEEDED  = LIST_OFF + (size_t)NT * CAP * 8;     // ~4.6 MB
}

struct Pre { float mx, my, z, a, b, c, radius; };

__device__ inline Pre preprocess(int g, const float* __restrict__ pos,
                                 const float* __restrict__ quat,
                                 const float* __restrict__ scl,
                                 const float* __restrict__ w2cr,
                                 const float* __restrict__ w2ct) {
  float p0 = pos[3*g+0], p1 = pos[3*g+1], p2 = pos[3*g+2];
  float qw = quat[4*g+0], qx = quat[4*g+1], qy = quat[4*g+2], qz = quat[4*g+3];
  float inv = 1.0f / sqrtf(qw*qw + qx*qx + qy*qy + qz*qz);
  qw *= inv; qx *= inv; qy *= inv; qz *= inv;
  float r00 = 1.f-2.f*(qy*qy+qz*qz), r01 = 2.f*(qx*qy-qw*qz), r02 = 2.f*(qx*qz+qw*qy);
  float r10 = 2.f*(qx*qy+qw*qz), r11 = 1.f-2.f*(qx*qx+qz*qz), r12 = 2.f*(qy*qz-qw*qx);
  float r20 = 2.f*(qx*qz-qw*qy), r21 = 2.f*(qy*qz+qw*qx), r22 = 1.f-2.f*(qx*qx+qy*qy);
  float e0 = expf(scl[3*g+0]); float s0 = e0*e0;
  float e1 = expf(scl[3*g+1]); float s1 = e1*e1;
  float e2 = expf(scl[3*g+2]); float s2 = e2*e2;
  float C00 = r00*r00*s0 + r01*r01*s1 + r02*r02*s2;
  float C01 = r00*r10*s0 + r01*r11*s1 + r02*r12*s2;
  float C02 = r00*r20*s0 + r01*r21*s1 + r02*r22*s2;
  float C11 = r10*r10*s0 + r11*r11*s1 + r12*r12*s2;
  float C12 = r10*r20*s0 + r11*r21*s1 + r12*r22*s2;
  float C22 = r20*r20*s0 + r21*r21*s1 + r22*r22*s2;
  float w00=w2cr[0],w01=w2cr[1],w02=w2cr[2];
  float w10=w2cr[3],w11=w2cr[4],w12=w2cr[5];
  float w20=w2cr[6],w21=w2cr[7],w22=w2cr[8];
  float x = w00*p0 + w01*p1 + w02*p2 + w2ct[0];
  float y = w10*p0 + w11*p1 + w12*p2 + w2ct[1];
  float z = w20*p0 + w21*p1 + w22*p2 + w2ct[2];
  float m00 = w00*C00 + w01*C01 + w02*C02;
  float m01 = w00*C01 + w01*C11 + w02*C12;
  float m02 = w00*C02 + w01*C12 + w02*C22;
  float m10 = w10*C00 + w11*C01 + w12*C02;
  float m11 = w10*C01 + w11*C11 + w12*C12;
  float m12 = w10*C02 + w11*C12 + w12*C22;
  float m20 = w20*C00 + w21*C01 + w22*C02;
  float m21 = w20*C01 + w21*C11 + w22*C12;
  float m22 = w20*C02 + w21*C12 + w22*C22;
  float v00 = m00*w00 + m01*w01 + m02*w02;
  float v01 = m00*w10 + m01*w11 + m02*w12;
  float v02 = m00*w20 + m01*w21 + m02*w22;
  float v10 = m10*w00 + m11*w01 + m12*w02;
  float v11 = m10*w10 + m11*w11 + m12*w12;
  float v12 = m10*w20 + m11*w21 + m12*w22;
  float v20 = m20*w00 + m21*w01 + m22*w02;
  float v21 = m20*w10 + m21*w11 + m22*w12;
  float v22 = m20*w20 + m21*w21 + m22*w22;
  float zc = fmaxf(z, 1e-6f);
  float iz = 1.0f / zc;
  float mx = x * iz, my = y * iz;
  float iz2 = iz * iz;
  float jx = -x * iz2, jy = -y * iz2;
  float a00 = iz*v00 + jx*v20, a01 = iz*v01 + jx*v21, a02 = iz*v02 + jx*v22;
  float a10 = iz*v10 + jy*v20, a11 = iz*v11 + jy*v21, a12 = iz*v12 + jy*v22;
  float A  = a00*iz + a02*jx + LP;
  float Bv = a01*iz + a02*jy;
  float Cv = a11*iz + a12*jy + LP;
  float mid = 0.5f*(A + Cv);
  float hh  = 0.5f*(A - Cv);
  float disc = fmaxf(hh*hh + Bv*Bv, 0.0f);
  float smax = sqrtf(fmaxf(mid + sqrtf(disc), 1e-12f));
  bool infr = (z > NEARP) && (fabsf(mx) < HALF_W) && (fabsf(my) < HALF_H);
  Pre r;
  r.mx = mx; r.my = my; r.z = z; r.a = A; r.b = Bv; r.c = Cv;
  r.radius = infr ? (3.0f * smax + THDIAG) : -1.0f;
  return r;
}

template <bool WITH_PAY>
__device__ inline void bitonic_sort(unsigned long long* key,
                                    unsigned long long* pay, int M) {
  for (int k = 2; k <= M; k <<= 1) {
    for (int j = k >> 1; j > 0; j >>= 1) {
      __syncthreads();
      for (int i = (int)threadIdx.x; i < M; i += (int)blockDim.x) {
        int ixj = i ^ j;
        if (ixj > i) {
          unsigned long long a = key[i], b = key[ixj];
          bool up = ((i & k) == 0);
          bool swp = up ? (a > b) : (a < b);
          if (swp) {
            key[i] = b; key[ixj] = a;
            if constexpr (WITH_PAY) {
              unsigned long long t = pay[i]; pay[i] = pay[ixj]; pay[ixj] = t;
            }
          }
        }
      }
    }
  }
  __syncthreads();
}

// ------------------- two-kernel fast path -------------------

__global__ __launch_bounds__(256)
void preprocess_bin(const float* __restrict__ pos, const float* __restrict__ rgb,
                    const float* __restrict__ opac, const float* __restrict__ quat,
                    const float* __restrict__ scl, const float* __restrict__ w2cr,
                    const float* __restrict__ w2ct, float* __restrict__ pm,
                    int* __restrict__ tcnt, unsigned long long* __restrict__ lists,
                    int n) {
  int g = blockIdx.x * 256 + (int)threadIdx.x;
  if (g >= n) return;
  Pre p = preprocess(g, pos, quat, scl, w2cr, w2ct);
  float det = fmaxf(p.a * p.c - p.b * p.b, 1e-12f);
  pm[IDX_MX*N_PAD+g]  = p.mx;
  pm[IDX_MY*N_PAD+g]  = p.my;
  pm[IDX_Z*N_PAD+g]   = p.z;
  pm[IDX_A*N_PAD+g]   = p.a;
  pm[IDX_B*N_PAD+g]   = p.b;
  pm[IDX_C*N_PAD+g]   = p.c;
  pm[IDX_IVD*N_PAD+g] = 1.0f / det;
  pm[IDX_OPA*N_PAD+g] = 1.0f / (1.0f + __expf(-opac[g]));
  pm[IDX_CR*N_PAD+g]  = 1.0f / (1.0f + __expf(-rgb[3*g+0]));
  pm[IDX_CG*N_PAD+g]  = 1.0f / (1.0f + __expf(-rgb[3*g+1]));
  pm[IDX_CB*N_PAD+g]  = 1.0f / (1.0f + __expf(-rgb[3*g+2]));
  if (p.radius < 0.0f) return;
  float r = p.radius;
  // tile center cx(tx) = (tx*16 + 8 - 128)/FX  ->  tx = (cx*FX + 120)/16
  int txlo = max(0,     (int)floorf(((p.mx - r) * FX + 120.0f) * 0.0625f));
  int txhi = min(NTX-1, (int)ceilf (((p.mx + r) * FX + 120.0f) * 0.0625f));
  int tylo = max(0,     (int)floorf(((p.my - r) * FY + 120.0f) * 0.0625f));
  int tyhi = min(NTX-1, (int)ceilf (((p.my + r) * FY + 120.0f) * 0.0625f));
  for (int ty = tylo; ty <= tyhi; ++ty) {
    float cy = (ty * TILE + TILE * 0.5f - H * 0.5f) / FY;
    float ddy = cy - p.my;
    for (int tx = txlo; tx <= txhi; ++tx) {
      float cx = (tx * TILE + TILE * 0.5f - W * 0.5f) / FX;
      float ddx = cx - p.mx;
      float dist = sqrtf(ddx * ddx + ddy * ddy);   // same formula as reference test
      if (dist <= r) {
        int t = ty * NTX + tx;
        int slot = atomicAdd(&tcnt[t], 1);
        if (slot < CAP)
          lists[(size_t)t * CAP + slot] =
              ((unsigned long long)__float_as_uint(dist) << 32) | (unsigned int)g;
      }
    }
  }
}

__global__ __launch_bounds__(256)
void render_tiles(const float* __restrict__ pm, const int* __restrict__ tcnt,
                  const unsigned long long* __restrict__ lists,
                  float* __restrict__ out) {
  __shared__ unsigned long long s_key[CAP];
  __shared__ float s_mx[K], s_my[K], s_a[K], s_b[K], s_c[K], s_ivd[K];
  __shared__ float s_opa[K], s_cr[K], s_cg[K], s_cb[K];

  const int t  = blockIdx.x;
  const int tx = t % NTX;
  const int ty = t / NTX;
  const int tid = (int)threadIdx.x;
  const unsigned long long* list = lists + (size_t)t * CAP;

  int cnt = min(tcnt[t], CAP);
  int cnt2;
  if (cnt > K) {
    int M = 1; while (M < cnt) M <<= 1;
    for (int i = tid; i < M; i += 256)
      s_key[i] = (i < cnt) ? list[i] : ~0ull;
    bitonic_sort<false>(s_key, nullptr, M);   // by (dist, idx) asc -> exact top-K
    for (int i = tid; i < K; i += 256) {
      int g = (int)(s_key[i] & 0xffffffffu);
      s_key[i] = ((unsigned long long)__float_as_uint(pm[IDX_Z*N_PAD+g]) << 32) |
                 (unsigned int)g;
    }
    bitonic_sort<false>(s_key, nullptr, K);   // by (z, idx) asc
    cnt2 = K;
  } else {
    cnt2 = cnt;
    int M = 1; while (M < cnt2) M <<= 1;
    if (M < 1) M = 1;
    for (int i = tid; i < M; i += 256) {
      if (i < cnt2) {
        int g = (int)(list[i] & 0xffffffffu);
        s_key[i] = ((unsigned long long)__float_as_uint(pm[IDX_Z*N_PAD+g]) << 32) |
                   (unsigned int)g;
      } else {
        s_key[i] = ~0ull;
      }
    }
    if (cnt2 > 1) bitonic_sort<false>(s_key, nullptr, M);
    else __syncthreads();
  }

  for (int i = tid; i < cnt2; i += 256) {
    int g = (int)(s_key[i] & 0xffffffffu);
    s_mx[i]  = pm[IDX_MX*N_PAD+g];
    s_my[i]  = pm[IDX_MY*N_PAD+g];
    s_a[i]   = pm[IDX_A*N_PAD+g];
    s_b[i]   = pm[IDX_B*N_PAD+g];
    s_c[i]   = pm[IDX_C*N_PAD+g];
    s_ivd[i] = pm[IDX_IVD*N_PAD+g];
    s_opa[i] = pm[IDX_OPA*N_PAD+g];
    s_cr[i]  = pm[IDX_CR*N_PAD+g];
    s_cg[i]  = pm[IDX_CG*N_PAD+g];
    s_cb[i]  = pm[IDX_CB*N_PAD+g];
  }
  __syncthreads();

  const int prow = tid / TILE, pcol = tid % TILE;
  const float u = ((float)(tx * TILE + pcol) + 0.5f - W * 0.5f) / FX;
  const float v = ((float)(ty * TILE + prow) + 0.5f - H * 0.5f) / FY;
  float T = 1.0f, accr = 0.0f, accg = 0.0f, accb = 0.0f;
  for (int k2 = 0; k2 < cnt2; ++k2) {
    float dx = u - s_mx[k2];
    float dy = v - s_my[k2];
    float maha = (s_c[k2]*dx*dx - 2.0f*s_b[k2]*dx*dy + s_a[k2]*dy*dy) * s_ivd[k2];
    float alpha = fminf(s_opa[k2] * __expf(-0.5f * maha), 0.99f);
    float w = alpha * T;
    accr += w * s_cr[k2];
    accg += w * s_cg[k2];
    accb += w * s_cb[k2];
    T *= (1.0f - alpha);
    if (T < 1e-7f) break;
  }
  const int row = ty * TILE + prow;
  const int col = tx * TILE + pcol;
  const int o = (row * W + col) * 3;
  out[o+0] = fminf(fmaxf(accr, 0.0f), 1.0f);
  out[o+1] = fminf(fmaxf(accg, 0.0f), 1.0f);
  out[o+2] = fminf(fmaxf(accb, 0.0f), 1.0f);
}

// ------------------- fallback monolith (round-1, passed) -------------------

__global__ __launch_bounds__(256)
void splat_tiles(const float* __restrict__ pos, const float* __restrict__ rgb,
                 const float* __restrict__ opac, const float* __restrict__ quat,
                 const float* __restrict__ scl, const float* __restrict__ w2cr,
                 const float* __restrict__ w2ct, float* __restrict__ out, int n) {
  __shared__ unsigned long long s_dkey[CAP];
  __shared__ unsigned long long s_zkey[CAP];
  __shared__ int s_cnt;
  __shared__ float s_mx[K], s_my[K], s_a[K], s_b[K], s_c[K], s_invdet[K];
  __shared__ float s_opa[K], s_cr[K], s_cg[K], s_cb[K];

  const int t  = blockIdx.x;
  const int tx = t % NTX;
  const int ty = t / NTX;
  const float cxc = (tx * TILE + TILE * 0.5f - W * 0.5f) / FX;
  const float cyc = (ty * TILE + TILE * 0.5f - H * 0.5f) / FY;

  if (threadIdx.x == 0) s_cnt = 0;
  __syncthreads();

  for (int g = (int)threadIdx.x; g < n; g += (int)blockDim.x) {
    Pre p = preprocess(g, pos, quat, scl, w2cr, w2ct);
    if (p.radius < 0.0f) continue;
    float ddx = cxc - p.mx, ddy = cyc - p.my;
    float dist = sqrtf(ddx * ddx + ddy * ddy);
    if (dist <= p.radius) {
      int slot = atomicAdd(&s_cnt, 1);
      if (slot < CAP) {
        s_dkey[slot] = ((unsigned long long)__float_as_uint(dist) << 32) | (unsigned int)g;
        s_zkey[slot] = ((unsigned long long)__float_as_uint(p.z)  << 32) | (unsigned int)g;
      }
    }
  }
  __syncthreads();
  int cnt = min(s_cnt, CAP);

  if (cnt > K) {
    int M = 1; while (M < cnt) M <<= 1;
    for (int i = cnt + (int)threadIdx.x; i < M; i += (int)blockDim.x)
      s_dkey[i] = ~0ull;
    __syncthreads();
    bitonic_sort<true>(s_dkey, s_zkey, M);
    cnt = K;
    bitonic_sort<false>(s_zkey, nullptr, K);
  } else if (cnt > 0) {
    int M = 1; while (M < cnt) M <<= 1;
    for (int i = cnt + (int)threadIdx.x; i < M; i += (int)blockDim.x)
      s_zkey[i] = ~0ull;
    __syncthreads();
    bitonic_sort<false>(s_zkey, nullptr, M);
  }

  for (int i = (int)threadIdx.x; i < cnt; i += (int)blockDim.x) {
    int g = (int)(s_zkey[i] & 0xffffffffu);
    Pre p = preprocess(g, pos, quat, scl, w2cr, w2ct);
    float det = fmaxf(p.a * p.c - p.b * p.b, 1e-12f);
    s_mx[i] = p.mx; s_my[i] = p.my;
    s_a[i] = p.a; s_b[i] = p.b; s_c[i] = p.c;
    s_invdet[i] = 1.0f / det;
    s_opa[i] = 1.0f / (1.0f + expf(-opac[g]));
    s_cr[i]  = 1.0f / (1.0f + expf(-rgb[3*g+0]));
    s_cg[i]  = 1.0f / (1.0f + expf(-rgb[3*g+1]));
    s_cb[i]  = 1.0f / (1.0f + expf(-rgb[3*g+2]));
  }
  __syncthreads();

  const int pi = (int)threadIdx.x;
  const int prow = pi / TILE, pcol = pi % TILE;
  const float u = ((float)(tx * TILE + pcol) + 0.5f - W * 0.5f) / FX;
  const float v = ((float)(ty * TILE + prow) + 0.5f - H * 0.5f) / FY;
  float T = 1.0f, accr = 0.0f, accg = 0.0f, accb = 0.0f;
  for (int k2 = 0; k2 < cnt; ++k2) {
    float dx = u - s_mx[k2];
    float dy = v - s_my[k2];
    float maha = (s_c[k2]*dx*dx - 2.0f*s_b[k2]*dx*dy + s_a[k2]*dy*dy) * s_invdet[k2];
    float alpha = fminf(s_opa[k2] * expf(-0.5f * maha), 0.99f);
    float w = alpha * T;
    accr += w * s_cr[k2];
    accg += w * s_cg[k2];
    accb += w * s_cb[k2];
    T *= (1.0f - alpha);
    if (T < 1e-7f) break;
  }
  const int row = ty * TILE + prow;
  const int col = tx * TILE + pcol;
  const int o = (row * W + col) * 3;
  out[o+0] = fminf(fmaxf(accr, 0.0f), 1.0f);
  out[o+1] = fminf(fmaxf(accg, 0.0f), 1.0f);
  out[o+2] = fminf(fmaxf(accb, 0.0f), 1.0f);
}

extern "C" void kernel_launch(void* const* d_in, const int* in_sizes, int n_in,
                              void* d_out, int out_size, void* d_ws, size_t ws_size,
                              hipStream_t stream) {
  const float* pos  = (const float*)d_in[0];
  const float* rgb  = (const float*)d_in[1];
  const float* opac = (const float*)d_in[2];
  const float* quat = (const float*)d_in[3];
  const float* scl  = (const float*)d_in[4];
  const float* w2cr = (const float*)d_in[5];
  const float* w2ct = (const float*)d_in[6];
  float* out = (float*)d_out;
  const int n = in_sizes[0] / 3;

  if (ws_size >= WS_NEEDED) {
    char* ws = (char*)d_ws;
    float* pm = (float*)ws;
    int* tcnt = (int*)(ws + CNT_OFF);
    unsigned long long* lists = (unsigned long long*)(ws + LIST_OFF);
    hipMemsetAsync(tcnt, 0, NT * sizeof(int), stream);
    preprocess_bin<<<(n + 255) / 256, 256, 0, stream>>>(
        pos, rgb, opac, quat, scl, w2cr, w2ct, pm, tcnt, lists, n);
    render_tiles<<<NT, 256, 0, stream>>>(pm, tcnt, lists, out);
  } else {
    splat_tiles<<<NT, 256, 0, stream>>>(pos, rgb, opac, quat, scl, w2cr, w2ct, out, n);
  }
}

// Round 3
// 45.941 us; speedup vs baseline: 1.4610x; 1.2940x over previous
//
#include <hip/hip_runtime.h>
#include <math.h>

namespace {
constexpr int W = 256, H = 256, TILE = 16, NTX = 16, NT = 256, K = 256;
constexpr float FX = 200.0f, FY = 200.0f, NEARP = 0.3f, MAGIC = 1.2f;
constexpr float LP = 0.3f / (FX * FX);
constexpr float HALF_W = W * MAGIC / 2.0f / FX;   // 0.768
constexpr float HALF_H = H * MAGIC / 2.0f / FY;   // 0.768
constexpr float THDIAG = 0.05656854249492381f;    // 0.5*sqrt((TILE/FX)^2+(TILE/FY)^2)
constexpr int CAP = 2048;
constexpr int N_PAD = 10240;
// ws layout: three float4 SoA arrays
constexpr size_t A_OFF = 0;                                  // (mx, my, radius, z)
constexpr size_t B_OFF = A_OFF + (size_t)N_PAD * 16;         // (a, b, c, 1/det)
constexpr size_t C_OFF = B_OFF + (size_t)N_PAD * 16;         // (opa, cr, cg, cb)
constexpr size_t WS_NEEDED = C_OFF + (size_t)N_PAD * 16;     // ~480 KB
}

// ---------------- preprocess: one eval per gaussian ----------------

__global__ __launch_bounds__(256)
void preprocess_k(const float* __restrict__ pos, const float* __restrict__ rgb,
                  const float* __restrict__ opac, const float* __restrict__ quat,
                  const float* __restrict__ scl, const float* __restrict__ w2cr,
                  const float* __restrict__ w2ct,
                  float4* __restrict__ pa, float4* __restrict__ pb,
                  float4* __restrict__ pc, int n) {
  int g = blockIdx.x * 256 + (int)threadIdx.x;
  if (g >= n) return;
  float p0 = pos[3*g+0], p1 = pos[3*g+1], p2 = pos[3*g+2];
  float qw = quat[4*g+0], qx = quat[4*g+1], qy = quat[4*g+2], qz = quat[4*g+3];
  float inv = 1.0f / sqrtf(qw*qw + qx*qx + qy*qy + qz*qz);
  qw *= inv; qx *= inv; qy *= inv; qz *= inv;
  float r00 = 1.f-2.f*(qy*qy+qz*qz), r01 = 2.f*(qx*qy-qw*qz), r02 = 2.f*(qx*qz+qw*qy);
  float r10 = 2.f*(qx*qy+qw*qz), r11 = 1.f-2.f*(qx*qx+qz*qz), r12 = 2.f*(qy*qz-qw*qx);
  float r20 = 2.f*(qx*qz-qw*qy), r21 = 2.f*(qy*qz+qw*qx), r22 = 1.f-2.f*(qx*qx+qy*qy);
  float e0 = expf(scl[3*g+0]); float s0 = e0*e0;
  float e1 = expf(scl[3*g+1]); float s1 = e1*e1;
  float e2 = expf(scl[3*g+2]); float s2 = e2*e2;
  float C00 = r00*r00*s0 + r01*r01*s1 + r02*r02*s2;
  float C01 = r00*r10*s0 + r01*r11*s1 + r02*r12*s2;
  float C02 = r00*r20*s0 + r01*r21*s1 + r02*r22*s2;
  float C11 = r10*r10*s0 + r11*r11*s1 + r12*r12*s2;
  float C12 = r10*r20*s0 + r11*r21*s1 + r12*r22*s2;
  float C22 = r20*r20*s0 + r21*r21*s1 + r22*r22*s2;
  float w00=w2cr[0],w01=w2cr[1],w02=w2cr[2];
  float w10=w2cr[3],w11=w2cr[4],w12=w2cr[5];
  float w20=w2cr[6],w21=w2cr[7],w22=w2cr[8];
  float x = w00*p0 + w01*p1 + w02*p2 + w2ct[0];
  float y = w10*p0 + w11*p1 + w12*p2 + w2ct[1];
  float z = w20*p0 + w21*p1 + w22*p2 + w2ct[2];
  float m00 = w00*C00 + w01*C01 + w02*C02;
  float m01 = w00*C01 + w01*C11 + w02*C12;
  float m02 = w00*C02 + w01*C12 + w02*C22;
  float m10 = w10*C00 + w11*C01 + w12*C02;
  float m11 = w10*C01 + w11*C11 + w12*C12;
  float m12 = w10*C02 + w11*C12 + w12*C22;
  float m20 = w20*C00 + w21*C01 + w22*C02;
  float m21 = w20*C01 + w21*C11 + w22*C12;
  float m22 = w20*C02 + w21*C12 + w22*C22;
  float v00 = m00*w00 + m01*w01 + m02*w02;
  float v01 = m00*w10 + m01*w11 + m02*w12;
  float v02 = m00*w20 + m01*w21 + m02*w22;
  float v10 = m10*w00 + m11*w01 + m12*w02;
  float v11 = m10*w10 + m11*w11 + m12*w12;
  float v12 = m10*w20 + m11*w21 + m12*w22;
  float v20 = m20*w00 + m21*w01 + m22*w02;
  float v21 = m20*w10 + m21*w11 + m22*w12;
  float v22 = m20*w20 + m21*w21 + m22*w22;
  float zc = fmaxf(z, 1e-6f);
  float iz = 1.0f / zc;
  float mx = x * iz, my = y * iz;
  float iz2 = iz * iz;
  float jx = -x * iz2, jy = -y * iz2;
  float a00 = iz*v00 + jx*v20, a01 = iz*v01 + jx*v21, a02 = iz*v02 + jx*v22;
  float a10 = iz*v10 + jy*v20, a11 = iz*v11 + jy*v21, a12 = iz*v12 + jy*v22;
  float A  = a00*iz + a02*jx + LP;
  float Bv = a01*iz + a02*jy;
  float Cv = a11*iz + a12*jy + LP;
  float mid = 0.5f*(A + Cv);
  float hh  = 0.5f*(A - Cv);
  float disc = fmaxf(hh*hh + Bv*Bv, 0.0f);
  float smax = sqrtf(fmaxf(mid + sqrtf(disc), 1e-12f));
  bool infr = (z > NEARP) && (fabsf(mx) < HALF_W) && (fabsf(my) < HALF_H);
  float radius = infr ? (3.0f * smax + THDIAG) : -1.0f;
  float det = fmaxf(A * Cv - Bv * Bv, 1e-12f);
  pa[g] = make_float4(mx, my, radius, z);
  pb[g] = make_float4(A, Bv, Cv, 1.0f / det);
  pc[g] = make_float4(1.0f / (1.0f + __expf(-opac[g])),
                      1.0f / (1.0f + __expf(-rgb[3*g+0])),
                      1.0f / (1.0f + __expf(-rgb[3*g+1])),
                      1.0f / (1.0f + __expf(-rgb[3*g+2])));
}

// ---------------- hybrid bitonic: shfl for j<=32, LDS for j>=64 ----------------

template <int S>  // elements per thread; M = S*256
__device__ inline void hsort(unsigned long long* key) {
  const int tid = (int)threadIdx.x;
  constexpr int M = S * 256;
  for (int k = 2; k <= M; k <<= 1) {
    for (int j = k >> 1; j >= 64; j >>= 1) {
      __syncthreads();
      #pragma unroll
      for (int s = 0; s < S; ++s) {
        int i = tid + (s << 8);
        int ixj = i ^ j;
        if (ixj > i) {
          unsigned long long a = key[i], b = key[ixj];
          bool up = ((i & k) == 0);
          if (up ? (a > b) : (a < b)) { key[i] = b; key[ixj] = a; }
        }
      }
    }
    __syncthreads();
    unsigned long long e[S];
    #pragma unroll
    for (int s = 0; s < S; ++s) e[s] = key[tid + (s << 8)];
    int j0 = ((k >> 1) < 32) ? (k >> 1) : 32;
    for (int j = j0; j >= 1; j >>= 1) {
      #pragma unroll
      for (int s = 0; s < S; ++s) {
        int i = tid + (s << 8);
        unsigned long long p = __shfl_xor(e[s], j, 64);
        bool up = ((i & k) == 0);
        bool lower = ((i & j) == 0);
        bool takeMin = (lower == up);
        bool pLess = (p < e[s]);
        // keys are unique (low 32 bits = gaussian id) so p != e[s]
        e[s] = (pLess == takeMin) ? p : e[s];
      }
    }
    #pragma unroll
    for (int s = 0; s < S; ++s) key[tid + (s << 8)] = e[s];
    __syncthreads();
  }
}

// ---------------- render: collect -> top-K -> z-sort -> blend ----------------

__global__ __launch_bounds__(256)
void render_k(const float4* __restrict__ pa, const float4* __restrict__ pb,
              const float4* __restrict__ pc, float* __restrict__ out, int n) {
  __shared__ unsigned long long s_key[CAP];
  __shared__ float4 s_p0[K];   // mx, my, a, b
  __shared__ float4 s_p1[K];   // c, ivd, opa, cr
  __shared__ float2 s_p2[K];   // cg, cb
  __shared__ int s_cnt;

  const int t  = (int)blockIdx.x;
  const int tx = t % NTX;
  const int ty = t / NTX;
  const int tid = (int)threadIdx.x;
  const float cxc = (tx * TILE + TILE * 0.5f - W * 0.5f) / FX;
  const float cyc = (ty * TILE + TILE * 0.5f - H * 0.5f) / FY;

  if (tid == 0) s_cnt = 0;
  __syncthreads();

  // collect: 1 coalesced float4 load per gaussian
  for (int g = tid; g < n; g += 256) {
    float4 v = pa[g];                   // (mx, my, radius, z)
    if (v.z < 0.0f) continue;
    float ddx = cxc - v.x, ddy = cyc - v.y;
    float dist = sqrtf(ddx * ddx + ddy * ddy);   // exact reference predicate
    if (dist <= v.z) {
      int slot = atomicAdd(&s_cnt, 1);
      if (slot < CAP)
        s_key[slot] = ((unsigned long long)__float_as_uint(dist) << 32) |
                      (unsigned int)g;
    }
  }
  __syncthreads();
  int cnt = min(s_cnt, CAP);
  int cnt2 = cnt;

  if (cnt > K) {
    // exact top-K by (dist, idx) ascending  == top_k on -dist
    int M = 512; while (M < cnt) M <<= 1;
    for (int i = cnt + tid; i < M; i += 256) s_key[i] = ~0ull;
    __syncthreads();
    if (M == 512) hsort<2>(s_key);
    else if (M == 1024) hsort<4>(s_key);
    else hsort<8>(s_key);
    // rebuild keys as (z, idx) for the K survivors
    {
      int g = (int)(s_key[tid] & 0xffffffffu);
      unsigned long long zk =
          ((unsigned long long)__float_as_uint(pa[g].w) << 32) | (unsigned int)g;
      __syncthreads();
      s_key[tid] = zk;
    }
    __syncthreads();
    hsort<1>(s_key);
    cnt2 = K;
  } else if (cnt > 0) {
    // rebuild as (z, idx), pad to 256, single sort
    unsigned long long zk = ~0ull;
    if (tid < cnt) {
      int g = (int)(s_key[tid] & 0xffffffffu);
      zk = ((unsigned long long)__float_as_uint(pa[g].w) << 32) | (unsigned int)g;
    }
    __syncthreads();
    s_key[tid] = zk;
    __syncthreads();
    hsort<1>(s_key);
  }

  // preload packed params for sorted survivors
  if (tid < cnt2) {
    int g = (int)(s_key[tid] & 0xffffffffu);
    float4 A = pa[g], B = pb[g], C = pc[g];
    s_p0[tid] = make_float4(A.x, A.y, B.x, B.y);
    s_p1[tid] = make_float4(B.z, B.w, C.x, C.y);
    s_p2[tid] = make_float2(C.z, C.w);
  }
  __syncthreads();

  // per-pixel front-to-back blend
  const int prow = tid / TILE, pcol = tid % TILE;
  const float u = ((float)(tx * TILE + pcol) + 0.5f - W * 0.5f) / FX;
  const float v = ((float)(ty * TILE + prow) + 0.5f - H * 0.5f) / FY;
  float T = 1.0f, accr = 0.0f, accg = 0.0f, accb = 0.0f;
  for (int k2 = 0; k2 < cnt2; ++k2) {
    float4 p0 = s_p0[k2];          // mx, my, a, b
    float4 p1 = s_p1[k2];          // c, ivd, opa, cr
    float2 p2 = s_p2[k2];          // cg, cb
    float dx = u - p0.x;
    float dy = v - p0.y;
    float maha = (p1.x*dx*dx - 2.0f*p0.w*dx*dy + p0.z*dy*dy) * p1.y;
    float alpha = fminf(p1.z * __expf(-0.5f * maha), 0.99f);
    float w = alpha * T;
    accr += w * p1.w;
    accg += w * p2.x;
    accb += w * p2.y;
    T *= (1.0f - alpha);
    if (T < 1e-7f) break;
  }
  const int row = ty * TILE + prow;
  const int col = tx * TILE + pcol;
  const int o = (row * W + col) * 3;
  out[o+0] = fminf(fmaxf(accr, 0.0f), 1.0f);
  out[o+1] = fminf(fmaxf(accg, 0.0f), 1.0f);
  out[o+2] = fminf(fmaxf(accb, 0.0f), 1.0f);
}

extern "C" void kernel_launch(void* const* d_in, const int* in_sizes, int n_in,
                              void* d_out, int out_size, void* d_ws, size_t ws_size,
                              hipStream_t stream) {
  const float* pos  = (const float*)d_in[0];
  const float* rgb  = (const float*)d_in[1];
  const float* opac = (const float*)d_in[2];
  const float* quat = (const float*)d_in[3];
  const float* scl  = (const float*)d_in[4];
  const float* w2cr = (const float*)d_in[5];
  const float* w2ct = (const float*)d_in[6];
  float* out = (float*)d_out;
  const int n = in_sizes[0] / 3;

  char* ws = (char*)d_ws;
  float4* pa = (float4*)(ws + A_OFF);
  float4* pb = (float4*)(ws + B_OFF);
  float4* pc = (float4*)(ws + C_OFF);
  preprocess_k<<<(n + 255) / 256, 256, 0, stream>>>(
      pos, rgb, opac, quat, scl, w2cr, w2ct, pa, pb, pc, n);
  render_k<<<NT, 256, 0, stream>>>(pa, pb, pc, out, n);
}

// Round 4
// 27.383 us; speedup vs baseline: 2.4511x; 1.6777x over previous
//
#include <hip/hip_runtime.h>
#include <math.h>

namespace {
constexpr int W = 256, H = 256, TILE = 16, NTX = 16, NT = 256, K = 256;
constexpr float FX = 200.0f, FY = 200.0f, NEARP = 0.3f, MAGIC = 1.2f;
constexpr float LP = 0.3f / (FX * FX);
constexpr float HALF_W = W * MAGIC / 2.0f / FX;   // 0.768
constexpr float HALF_H = H * MAGIC / 2.0f / FY;   // 0.768
constexpr float THDIAG = 0.05656854249492381f;    // 0.5*sqrt((TILE/FX)^2+(TILE/FY)^2)
constexpr int CAP = 2048;
constexpr int N_PAD = 10240;
constexpr int BT = 1024;                          // render block threads
// ws layout: three float4 SoA arrays
constexpr size_t A_OFF = 0;                                  // (mx, my, radius, z)
constexpr size_t B_OFF = A_OFF + (size_t)N_PAD * 16;         // (a, b, c, 1/det)
constexpr size_t C_OFF = B_OFF + (size_t)N_PAD * 16;         // (opa, cr, cg, cb)
}

// ---------------- preprocess: one eval per gaussian ----------------

__global__ __launch_bounds__(256)
void preprocess_k(const float* __restrict__ pos, const float* __restrict__ rgb,
                  const float* __restrict__ opac, const float* __restrict__ quat,
                  const float* __restrict__ scl, const float* __restrict__ w2cr,
                  const float* __restrict__ w2ct,
                  float4* __restrict__ pa, float4* __restrict__ pb,
                  float4* __restrict__ pc, int n) {
  int g = blockIdx.x * 256 + (int)threadIdx.x;
  if (g >= n) return;
  float p0 = pos[3*g+0], p1 = pos[3*g+1], p2 = pos[3*g+2];
  float qw = quat[4*g+0], qx = quat[4*g+1], qy = quat[4*g+2], qz = quat[4*g+3];
  float inv = 1.0f / sqrtf(qw*qw + qx*qx + qy*qy + qz*qz);
  qw *= inv; qx *= inv; qy *= inv; qz *= inv;
  float r00 = 1.f-2.f*(qy*qy+qz*qz), r01 = 2.f*(qx*qy-qw*qz), r02 = 2.f*(qx*qz+qw*qy);
  float r10 = 2.f*(qx*qy+qw*qz), r11 = 1.f-2.f*(qx*qx+qz*qz), r12 = 2.f*(qy*qz-qw*qx);
  float r20 = 2.f*(qx*qz-qw*qy), r21 = 2.f*(qy*qz+qw*qx), r22 = 1.f-2.f*(qx*qx+qy*qy);
  float e0 = expf(scl[3*g+0]); float s0 = e0*e0;
  float e1 = expf(scl[3*g+1]); float s1 = e1*e1;
  float e2 = expf(scl[3*g+2]); float s2 = e2*e2;
  float C00 = r00*r00*s0 + r01*r01*s1 + r02*r02*s2;
  float C01 = r00*r10*s0 + r01*r11*s1 + r02*r12*s2;
  float C02 = r00*r20*s0 + r01*r21*s1 + r02*r22*s2;
  float C11 = r10*r10*s0 + r11*r11*s1 + r12*r12*s2;
  float C12 = r10*r20*s0 + r11*r21*s1 + r12*r22*s2;
  float C22 = r20*r20*s0 + r21*r21*s1 + r22*r22*s2;
  float w00=w2cr[0],w01=w2cr[1],w02=w2cr[2];
  float w10=w2cr[3],w11=w2cr[4],w12=w2cr[5];
  float w20=w2cr[6],w21=w2cr[7],w22=w2cr[8];
  float x = w00*p0 + w01*p1 + w02*p2 + w2ct[0];
  float y = w10*p0 + w11*p1 + w12*p2 + w2ct[1];
  float z = w20*p0 + w21*p1 + w22*p2 + w2ct[2];
  float m00 = w00*C00 + w01*C01 + w02*C02;
  float m01 = w00*C01 + w01*C11 + w02*C12;
  float m02 = w00*C02 + w01*C12 + w02*C22;
  float m10 = w10*C00 + w11*C01 + w12*C02;
  float m11 = w10*C01 + w11*C11 + w12*C12;
  float m12 = w10*C02 + w11*C12 + w12*C22;
  float m20 = w20*C00 + w21*C01 + w22*C02;
  float m21 = w20*C01 + w21*C11 + w22*C12;
  float m22 = w20*C02 + w21*C12 + w22*C22;
  float v00 = m00*w00 + m01*w01 + m02*w02;
  float v01 = m00*w10 + m01*w11 + m02*w12;
  float v02 = m00*w20 + m01*w21 + m02*w22;
  float v10 = m10*w00 + m11*w01 + m12*w02;
  float v11 = m10*w10 + m11*w11 + m12*w12;
  float v12 = m10*w20 + m11*w21 + m12*w22;
  float v20 = m20*w00 + m21*w01 + m22*w02;
  float v21 = m20*w10 + m21*w11 + m22*w12;
  float v22 = m20*w20 + m21*w21 + m22*w22;
  float zc = fmaxf(z, 1e-6f);
  float iz = 1.0f / zc;
  float mx = x * iz, my = y * iz;
  float iz2 = iz * iz;
  float jx = -x * iz2, jy = -y * iz2;
  float a00 = iz*v00 + jx*v20, a01 = iz*v01 + jx*v21, a02 = iz*v02 + jx*v22;
  float a10 = iz*v10 + jy*v20, a11 = iz*v11 + jy*v21, a12 = iz*v12 + jy*v22;
  float A  = a00*iz + a02*jx + LP;
  float Bv = a01*iz + a02*jy;
  float Cv = a11*iz + a12*jy + LP;
  float mid = 0.5f*(A + Cv);
  float hh  = 0.5f*(A - Cv);
  float disc = fmaxf(hh*hh + Bv*Bv, 0.0f);
  float smax = sqrtf(fmaxf(mid + sqrtf(disc), 1e-12f));
  bool infr = (z > NEARP) && (fabsf(mx) < HALF_W) && (fabsf(my) < HALF_H);
  float radius = infr ? (3.0f * smax + THDIAG) : -1.0f;
  float det = fmaxf(A * Cv - Bv * Bv, 1e-12f);
  pa[g] = make_float4(mx, my, radius, z);
  pb[g] = make_float4(A, Bv, Cv, 1.0f / det);
  pc[g] = make_float4(1.0f / (1.0f + __expf(-opac[g])),
                      1.0f / (1.0f + __expf(-rgb[3*g+0])),
                      1.0f / (1.0f + __expf(-rgb[3*g+1])),
                      1.0f / (1.0f + __expf(-rgb[3*g+2])));
}

// ------- hybrid bitonic, 1024 threads, S elems/thread, runtime M (pow2) -------
// shfl for j<=32 (in-register), LDS for j>=64. Uniform barriers.

template <int S>
__device__ inline void hsortN(unsigned long long* key, int M) {
  const int tid = (int)threadIdx.x;
  __syncthreads();                       // producer of key[] may be another thread
  unsigned long long e[S];
  #pragma unroll
  for (int s = 0; s < S; ++s) {
    int i = tid + (s << 10);
    e[s] = (i < M) ? key[i] : ~0ull;
  }
  for (int k = 2; k <= M; k <<= 1) {
    for (int j = k >> 1; j >= 64; j >>= 1) {
      __syncthreads();
      #pragma unroll
      for (int s = 0; s < S; ++s) {
        int i = tid + (s << 10);
        if (i < M) key[i] = e[s];
      }
      __syncthreads();
      #pragma unroll
      for (int s = 0; s < S; ++s) {
        int i = tid + (s << 10);
        if (i < M) {
          unsigned long long p = key[i ^ j];
          bool takeMin = (((i & j) == 0) == ((i & k) == 0));
          e[s] = ((p < e[s]) == takeMin) ? p : e[s];   // keys unique
        }
      }
    }
    int j0 = ((k >> 1) < 32) ? (k >> 1) : 32;
    for (int j = j0; j >= 1; j >>= 1) {
      #pragma unroll
      for (int s = 0; s < S; ++s) {
        int i = tid + (s << 10);
        unsigned long long p = __shfl_xor(e[s], j, 64);
        bool takeMin = (((i & j) == 0) == ((i & k) == 0));
        e[s] = ((p < e[s]) == takeMin) ? p : e[s];
      }
    }
  }
  __syncthreads();
  #pragma unroll
  for (int s = 0; s < S; ++s) {
    int i = tid + (s << 10);
    if (i < M) key[i] = e[s];
  }
  __syncthreads();
}

// ---------------- render: collect -> top-K -> z-sort -> split-k blend ----------------

__global__ __launch_bounds__(BT)
void render_k(const float4* __restrict__ pa, const float4* __restrict__ pb,
              const float4* __restrict__ pc, float* __restrict__ out, int n) {
  __shared__ unsigned long long s_key[CAP];
  __shared__ float4 s_p0[K];     // mx, my, a, b
  __shared__ float4 s_p1[K];     // c, ivd, opa, cr
  __shared__ float2 s_p2[K];     // cg, cb
  __shared__ float4 s_part[BT];  // partial (r, g, b, T)
  __shared__ int s_cnt;

  const int t  = (int)blockIdx.x;
  const int tx = t % NTX;
  const int ty = t / NTX;
  const int tid = (int)threadIdx.x;
  const int lane = tid & 63;
  const float cxc = (tx * TILE + TILE * 0.5f - W * 0.5f) / FX;
  const float cyc = (ty * TILE + TILE * 0.5f - H * 0.5f) / FY;

  if (tid == 0) s_cnt = 0;
  __syncthreads();

  // ---- collect: coalesced float4 load + wave-aggregated LDS append ----
  for (int g = tid; g < n; g += BT) {
    float4 v = pa[g];                 // (mx, my, radius, z)
    float ddx = cxc - v.x, ddy = cyc - v.y;
    float dist = sqrtf(ddx * ddx + ddy * ddy);
    bool hit = (v.z >= 0.0f) && (dist <= v.z);
    unsigned long long m = __ballot(hit);
    if (m) {
      int leader = __ffsll((long long)m) - 1;
      int base = 0;
      if (lane == leader) base = atomicAdd(&s_cnt, __popcll(m));
      base = __shfl(base, leader, 64);
      if (hit) {
        int slot = base + __popcll(m & ((1ull << lane) - 1ull));
        if (slot < CAP)
          s_key[slot] = ((unsigned long long)__float_as_uint(dist) << 32) |
                        (unsigned int)g;
      }
    }
  }
  __syncthreads();
  int cnt = min(s_cnt, CAP);
  int cnt2 = cnt;

  if (cnt > K) {
    // exact top-K by (dist, idx) ascending == top_k on -dist
    int M = 512; while (M < cnt) M <<= 1;
    for (int i = cnt + tid; i < M; i += BT) s_key[i] = ~0ull;
    if (M <= 1024) hsortN<1>(s_key, M);
    else           hsortN<2>(s_key, 2048);
    // rebuild keys as (z, idx) for the K survivors (own-slot rewrite)
    if (tid < K) {
      int g = (int)(s_key[tid] & 0xffffffffu);
      s_key[tid] = ((unsigned long long)__float_as_uint(pa[g].w) << 32) |
                   (unsigned int)g;
    }
    hsortN<1>(s_key, K);
    cnt2 = K;
  } else if (cnt > 0) {
    int M = 2; while (M < cnt) M <<= 1;
    if (tid < cnt) {
      int g = (int)(s_key[tid] & 0xffffffffu);
      s_key[tid] = ((unsigned long long)__float_as_uint(pa[g].w) << 32) |
                   (unsigned int)g;
    }
    for (int i = cnt + tid; i < M; i += BT) s_key[i] = ~0ull;
    hsortN<1>(s_key, M);
  }

  // ---- gather packed params for sorted survivors ----
  if (tid < cnt2) {
    int g = (int)(s_key[tid] & 0xffffffffu);
    float4 A = pa[g], B = pb[g], C = pc[g];
    s_p0[tid] = make_float4(A.x, A.y, B.x, B.y);
    s_p1[tid] = make_float4(B.z, B.w, C.x, C.y);
    s_p2[tid] = make_float2(C.z, C.w);
  }
  __syncthreads();

  // ---- split-k blend: 4 threads per pixel, quarter of list each ----
  const int p    = tid & 255;
  const int q    = tid >> 8;
  const int prow = p / TILE, pcol = p % TILE;
  const float u = ((float)(tx * TILE + pcol) + 0.5f - W * 0.5f) / FX;
  const float v = ((float)(ty * TILE + prow) + 0.5f - H * 0.5f) / FY;
  const int chunk = (cnt2 + 3) >> 2;
  const int k0 = q * chunk;
  const int k1 = min(cnt2, k0 + chunk);
  float T = 1.0f, accr = 0.0f, accg = 0.0f, accb = 0.0f;
  for (int k2 = k0; k2 < k1; ++k2) {
    float4 p0 = s_p0[k2];          // mx, my, a, b
    float4 p1 = s_p1[k2];          // c, ivd, opa, cr
    float2 p2 = s_p2[k2];          // cg, cb
    float dx = u - p0.x;
    float dy = v - p0.y;
    float maha = (p1.x*dx*dx - 2.0f*p0.w*dx*dy + p0.z*dy*dy) * p1.y;
    float alpha = fminf(p1.z * __expf(-0.5f * maha), 0.99f);
    float w = alpha * T;
    accr += w * p1.w;
    accg += w * p2.x;
    accb += w * p2.y;
    T *= (1.0f - alpha);
  }
  s_part[tid] = make_float4(accr, accg, accb, T);
  __syncthreads();

  if (q == 0) {
    float4 P0 = s_part[p];
    float4 P1 = s_part[p + 256];
    float4 P2 = s_part[p + 512];
    float4 P3 = s_part[p + 768];
    // c = c0 + T0*(c1 + T1*(c2 + T2*c3))  — same order as serial blend
    float r = P0.x + P0.w * (P1.x + P1.w * (P2.x + P2.w * P3.x));
    float g = P0.y + P0.w * (P1.y + P1.w * (P2.y + P2.w * P3.y));
    float b = P0.z + P0.w * (P1.z + P1.w * (P2.z + P2.w * P3.z));
    const int row = ty * TILE + prow;
    const int col = tx * TILE + pcol;
    const int o = (row * W + col) * 3;
    out[o+0] = fminf(fmaxf(r, 0.0f), 1.0f);
    out[o+1] = fminf(fmaxf(g, 0.0f), 1.0f);
    out[o+2] = fminf(fmaxf(b, 0.0f), 1.0f);
  }
}

extern "C" void kernel_launch(void* const* d_in, const int* in_sizes, int n_in,
                              void* d_out, int out_size, void* d_ws, size_t ws_size,
                              hipStream_t stream) {
  const float* pos  = (const float*)d_in[0];
  const float* rgb  = (const float*)d_in[1];
  const float* opac = (const float*)d_in[2];
  const float* quat = (const float*)d_in[3];
  const float* scl  = (const float*)d_in[4];
  const float* w2cr = (const float*)d_in[5];
  const float* w2ct = (const float*)d_in[6];
  float* out = (float*)d_out;
  const int n = in_sizes[0] / 3;

  char* ws = (char*)d_ws;
  float4* pa = (float4*)(ws + A_OFF);
  float4* pb = (float4*)(ws + B_OFF);
  float4* pc = (float4*)(ws + C_OFF);
  preprocess_k<<<(n + 255) / 256, 256, 0, stream>>>(
      pos, rgb, opac, quat, scl, w2cr, w2ct, pa, pb, pc, n);
  render_k<<<NT, BT, 0, stream>>>(pa, pb, pc, out, n);
}

// Round 5
// 26.443 us; speedup vs baseline: 2.5383x; 1.0355x over previous
//
#include <hip/hip_runtime.h>
#include <math.h>

namespace {
constexpr int W = 256, H = 256, TILE = 16, NTX = 16, NT = 256, K = 256;
constexpr float FX = 200.0f, FY = 200.0f, NEARP = 0.3f, MAGIC = 1.2f;
constexpr float LP = 0.3f / (FX * FX);
constexpr float HALF_W = W * MAGIC / 2.0f / FX;   // 0.768
constexpr float HALF_H = H * MAGIC / 2.0f / FY;   // 0.768
constexpr float THDIAG = 0.05656854249492381f;    // 0.5*sqrt((TILE/FX)^2+(TILE/FY)^2)
constexpr int CAP = 2048;
constexpr int N_PAD = 10240;
constexpr int BT = 1024;                          // render block threads
// ws layout: three float4 SoA arrays
constexpr size_t A_OFF = 0;                                  // (mx, my, radius, z)
constexpr size_t B_OFF = A_OFF + (size_t)N_PAD * 16;         // (a, b, c, 1/det)
constexpr size_t C_OFF = B_OFF + (size_t)N_PAD * 16;         // (opa, cr, cg, cb)
}

// ---------------- preprocess: one eval per gaussian ----------------

__global__ __launch_bounds__(256)
void preprocess_k(const float* __restrict__ pos, const float* __restrict__ rgb,
                  const float* __restrict__ opac, const float* __restrict__ quat,
                  const float* __restrict__ scl, const float* __restrict__ w2cr,
                  const float* __restrict__ w2ct,
                  float4* __restrict__ pa, float4* __restrict__ pb,
                  float4* __restrict__ pc, int n) {
  int g = blockIdx.x * 256 + (int)threadIdx.x;
  if (g >= n) return;
  float p0 = pos[3*g+0], p1 = pos[3*g+1], p2 = pos[3*g+2];
  float qw = quat[4*g+0], qx = quat[4*g+1], qy = quat[4*g+2], qz = quat[4*g+3];
  float inv = 1.0f / sqrtf(qw*qw + qx*qx + qy*qy + qz*qz);
  qw *= inv; qx *= inv; qy *= inv; qz *= inv;
  float r00 = 1.f-2.f*(qy*qy+qz*qz), r01 = 2.f*(qx*qy-qw*qz), r02 = 2.f*(qx*qz+qw*qy);
  float r10 = 2.f*(qx*qy+qw*qz), r11 = 1.f-2.f*(qx*qx+qz*qz), r12 = 2.f*(qy*qz-qw*qx);
  float r20 = 2.f*(qx*qz-qw*qy), r21 = 2.f*(qy*qz+qw*qx), r22 = 1.f-2.f*(qx*qx+qy*qy);
  float e0 = expf(scl[3*g+0]); float s0 = e0*e0;
  float e1 = expf(scl[3*g+1]); float s1 = e1*e1;
  float e2 = expf(scl[3*g+2]); float s2 = e2*e2;
  float C00 = r00*r00*s0 + r01*r01*s1 + r02*r02*s2;
  float C01 = r00*r10*s0 + r01*r11*s1 + r02*r12*s2;
  float C02 = r00*r20*s0 + r01*r21*s1 + r02*r22*s2;
  float C11 = r10*r10*s0 + r11*r11*s1 + r12*r12*s2;
  float C12 = r10*r20*s0 + r11*r21*s1 + r12*r22*s2;
  float C22 = r20*r20*s0 + r21*r21*s1 + r22*r22*s2;
  float w00=w2cr[0],w01=w2cr[1],w02=w2cr[2];
  float w10=w2cr[3],w11=w2cr[4],w12=w2cr[5];
  float w20=w2cr[6],w21=w2cr[7],w22=w2cr[8];
  float x = w00*p0 + w01*p1 + w02*p2 + w2ct[0];
  float y = w10*p0 + w11*p1 + w12*p2 + w2ct[1];
  float z = w20*p0 + w21*p1 + w22*p2 + w2ct[2];
  float m00 = w00*C00 + w01*C01 + w02*C02;
  float m01 = w00*C01 + w01*C11 + w02*C12;
  float m02 = w00*C02 + w01*C12 + w02*C22;
  float m10 = w10*C00 + w11*C01 + w12*C02;
  float m11 = w10*C01 + w11*C11 + w12*C12;
  float m12 = w10*C02 + w11*C12 + w12*C22;
  float m20 = w20*C00 + w21*C01 + w22*C02;
  float m21 = w20*C01 + w21*C11 + w22*C12;
  float m22 = w20*C02 + w21*C12 + w22*C22;
  float v00 = m00*w00 + m01*w01 + m02*w02;
  float v01 = m00*w10 + m01*w11 + m02*w12;
  float v02 = m00*w20 + m01*w21 + m02*w22;
  float v10 = m10*w00 + m11*w01 + m12*w02;
  float v11 = m10*w10 + m11*w11 + m12*w12;
  float v12 = m10*w20 + m11*w21 + m12*w22;
  float v20 = m20*w00 + m21*w01 + m22*w02;
  float v21 = m20*w10 + m21*w11 + m22*w12;
  float v22 = m20*w20 + m21*w21 + m22*w22;
  float zc = fmaxf(z, 1e-6f);
  float iz = 1.0f / zc;
  float mx = x * iz, my = y * iz;
  float iz2 = iz * iz;
  float jx = -x * iz2, jy = -y * iz2;
  float a00 = iz*v00 + jx*v20, a01 = iz*v01 + jx*v21, a02 = iz*v02 + jx*v22;
  float a10 = iz*v10 + jy*v20, a11 = iz*v11 + jy*v21, a12 = iz*v12 + jy*v22;
  float A  = a00*iz + a02*jx + LP;
  float Bv = a01*iz + a02*jy;
  float Cv = a11*iz + a12*jy + LP;
  float mid = 0.5f*(A + Cv);
  float hh  = 0.5f*(A - Cv);
  float disc = fmaxf(hh*hh + Bv*Bv, 0.0f);
  float smax = sqrtf(fmaxf(mid + sqrtf(disc), 1e-12f));
  bool infr = (z > NEARP) && (fabsf(mx) < HALF_W) && (fabsf(my) < HALF_H);
  float radius = infr ? (3.0f * smax + THDIAG) : -1.0f;
  float det = fmaxf(A * Cv - Bv * Bv, 1e-12f);
  pa[g] = make_float4(mx, my, radius, z);
  pb[g] = make_float4(A, Bv, Cv, 1.0f / det);
  pc[g] = make_float4(1.0f / (1.0f + __expf(-opac[g])),
                      1.0f / (1.0f + __expf(-rgb[3*g+0])),
                      1.0f / (1.0f + __expf(-rgb[3*g+1])),
                      1.0f / (1.0f + __expf(-rgb[3*g+2])));
}

// ------- hybrid bitonic, 1024 threads, S elems/thread, runtime M (pow2) -------
// Used only on the rare cnt>K path. shfl for j<=32, LDS for j>=64.

template <int S>
__device__ inline void hsortN(unsigned long long* key, int M) {
  const int tid = (int)threadIdx.x;
  __syncthreads();                       // producer of key[] may be another thread
  unsigned long long e[S];
  #pragma unroll
  for (int s = 0; s < S; ++s) {
    int i = tid + (s << 10);
    e[s] = (i < M) ? key[i] : ~0ull;
  }
  for (int k = 2; k <= M; k <<= 1) {
    for (int j = k >> 1; j >= 64; j >>= 1) {
      __syncthreads();
      #pragma unroll
      for (int s = 0; s < S; ++s) {
        int i = tid + (s << 10);
        if (i < M) key[i] = e[s];
      }
      __syncthreads();
      #pragma unroll
      for (int s = 0; s < S; ++s) {
        int i = tid + (s << 10);
        if (i < M) {
          unsigned long long p = key[i ^ j];
          bool takeMin = (((i & j) == 0) == ((i & k) == 0));
          e[s] = ((p < e[s]) == takeMin) ? p : e[s];   // keys unique
        }
      }
    }
    int j0 = ((k >> 1) < 32) ? (k >> 1) : 32;
    for (int j = j0; j >= 1; j >>= 1) {
      #pragma unroll
      for (int s = 0; s < S; ++s) {
        int i = tid + (s << 10);
        unsigned long long p = __shfl_xor(e[s], j, 64);
        bool takeMin = (((i & j) == 0) == ((i & k) == 0));
        e[s] = ((p < e[s]) == takeMin) ? p : e[s];
      }
    }
  }
  __syncthreads();
  #pragma unroll
  for (int s = 0; s < S; ++s) {
    int i = tid + (s << 10);
    if (i < M) key[i] = e[s];
  }
  __syncthreads();
}

// ---------------- render: collect -> (topK) -> rank z-sort -> split-k blend ----------------

__global__ __launch_bounds__(BT)
void render_k(const float4* __restrict__ pa, const float4* __restrict__ pb,
              const float4* __restrict__ pc, float* __restrict__ out, int n) {
  __shared__ unsigned long long s_dkey[CAP];   // (dist_bits<<32)|g
  __shared__ unsigned long long s_zkey[CAP];   // (z_bits<<32)|g
  __shared__ int s_rank[K];
  __shared__ float4 s_p0[K];     // mx, my, a, b
  __shared__ float4 s_p1[K];     // c, ivd, opa, cr
  __shared__ float2 s_p2[K];     // cg, cb
  __shared__ float4 s_part[BT];  // partial (r, g, b, T)
  __shared__ int s_cnt;

  const int t  = (int)blockIdx.x;
  const int tx = t % NTX;
  const int ty = t / NTX;
  const int tid = (int)threadIdx.x;
  const int lane = tid & 63;
  const float cxc = (tx * TILE + TILE * 0.5f - W * 0.5f) / FX;
  const float cyc = (ty * TILE + TILE * 0.5f - H * 0.5f) / FY;

  if (tid == 0) s_cnt = 0;
  if (tid < K) s_rank[tid] = 0;
  __syncthreads();

  // ---- collect: coalesced float4 load + wave-aggregated LDS append ----
  for (int g = tid; g < n; g += BT) {
    float4 v = pa[g];                 // (mx, my, radius, z)
    float ddx = cxc - v.x, ddy = cyc - v.y;
    float dist = sqrtf(ddx * ddx + ddy * ddy);
    bool hit = (v.z >= 0.0f) && (dist <= v.z);
    unsigned long long m = __ballot(hit);
    if (m) {
      int leader = __ffsll((long long)m) - 1;
      int base = 0;
      if (lane == leader) base = atomicAdd(&s_cnt, __popcll(m));
      base = __shfl(base, leader, 64);
      if (hit) {
        int slot = base + __popcll(m & ((1ull << lane) - 1ull));
        if (slot < CAP) {
          s_dkey[slot] = ((unsigned long long)__float_as_uint(dist) << 32) |
                         (unsigned int)g;
          s_zkey[slot] = ((unsigned long long)__float_as_uint(v.w) << 32) |
                         (unsigned int)g;
        }
      }
    }
  }
  __syncthreads();
  int cnt = min(s_cnt, CAP);
  int cnt2 = cnt;

  if (cnt > K) {
    // rare path: exact top-K by (dist, idx) ascending == top_k on -dist
    int M = 512; while (M < cnt) M <<= 1;
    for (int i = cnt + tid; i < M; i += BT) s_dkey[i] = ~0ull;
    if (M <= 1024) hsortN<1>(s_dkey, M);
    else           hsortN<2>(s_dkey, 2048);
    // rebuild z-keys for the K survivors
    if (tid < K) {
      int g = (int)(s_dkey[tid] & 0xffffffffu);
      s_zkey[tid] = ((unsigned long long)__float_as_uint(pa[g].w) << 32) |
                    (unsigned int)g;
    }
    __syncthreads();
    cnt2 = K;
  }

  // ---- rank sort by (z, idx): all 1024 threads, 64 broadcast reads each ----
  {
    const int e = tid & 255;
    const int q = tid >> 8;
    if (e < cnt2) {
      unsigned long long mykey = s_zkey[e];
      int jlo = q * 64;
      int jhi = min(cnt2, jlo + 64);
      int partial = 0;
      for (int j = jlo; j < jhi; ++j)
        partial += (s_zkey[j] < mykey) ? 1 : 0;   // keys unique
      if (partial) atomicAdd(&s_rank[e], partial);
    }
  }
  __syncthreads();

  // ---- scatter params directly to rank position ----
  if (tid < cnt2) {
    int g = (int)(s_zkey[tid] & 0xffffffffu);
    int r = s_rank[tid];
    float4 A = pa[g], B = pb[g], C = pc[g];
    s_p0[r] = make_float4(A.x, A.y, B.x, B.y);
    s_p1[r] = make_float4(B.z, B.w, C.x, C.y);
    s_p2[r] = make_float2(C.z, C.w);
  }
  __syncthreads();

  // ---- split-k blend: 4 threads per pixel, quarter of list each ----
  const int p    = tid & 255;
  const int q    = tid >> 8;
  const int prow = p / TILE, pcol = p % TILE;
  const float u = ((float)(tx * TILE + pcol) + 0.5f - W * 0.5f) / FX;
  const float v = ((float)(ty * TILE + prow) + 0.5f - H * 0.5f) / FY;
  const int chunk = (cnt2 + 3) >> 2;
  const int k0 = q * chunk;
  const int k1 = min(cnt2, k0 + chunk);
  float T = 1.0f, accr = 0.0f, accg = 0.0f, accb = 0.0f;
  for (int k2 = k0; k2 < k1; ++k2) {
    float4 p0 = s_p0[k2];          // mx, my, a, b
    float4 p1 = s_p1[k2];          // c, ivd, opa, cr
    float2 p2 = s_p2[k2];          // cg, cb
    float dx = u - p0.x;
    float dy = v - p0.y;
    float maha = (p1.x*dx*dx - 2.0f*p0.w*dx*dy + p0.z*dy*dy) * p1.y;
    float alpha = fminf(p1.z * __expf(-0.5f * maha), 0.99f);
    float w = alpha * T;
    accr += w * p1.w;
    accg += w * p2.x;
    accb += w * p2.y;
    T *= (1.0f - alpha);
  }
  s_part[tid] = make_float4(accr, accg, accb, T);
  __syncthreads();

  if (q == 0) {
    float4 P0 = s_part[p];
    float4 P1 = s_part[p + 256];
    float4 P2 = s_part[p + 512];
    float4 P3 = s_part[p + 768];
    // c = c0 + T0*(c1 + T1*(c2 + T2*c3))  — same order as serial blend
    float r = P0.x + P0.w * (P1.x + P1.w * (P2.x + P2.w * P3.x));
    float g = P0.y + P0.w * (P1.y + P1.w * (P2.y + P2.w * P3.y));
    float b = P0.z + P0.w * (P1.z + P1.w * (P2.z + P2.w * P3.z));
    const int row = ty * TILE + prow;
    const int col = tx * TILE + pcol;
    const int o = (row * W + col) * 3;
    out[o+0] = fminf(fmaxf(r, 0.0f), 1.0f);
    out[o+1] = fminf(fmaxf(g, 0.0f), 1.0f);
    out[o+2] = fminf(fmaxf(b, 0.0f), 1.0f);
  }
}

extern "C" void kernel_launch(void* const* d_in, const int* in_sizes, int n_in,
                              void* d_out, int out_size, void* d_ws, size_t ws_size,
                              hipStream_t stream) {
  const float* pos  = (const float*)d_in[0];
  const float* rgb  = (const float*)d_in[1];
  const float* opac = (const float*)d_in[2];
  const float* quat = (const float*)d_in[3];
  const float* scl  = (const float*)d_in[4];
  const float* w2cr = (const float*)d_in[5];
  const float* w2ct = (const float*)d_in[6];
  float* out = (float*)d_out;
  const int n = in_sizes[0] / 3;

  char* ws = (char*)d_ws;
  float4* pa = (float4*)(ws + A_OFF);
  float4* pb = (float4*)(ws + B_OFF);
  float4* pc = (float4*)(ws + C_OFF);
  preprocess_k<<<(n + 255) / 256, 256, 0, stream>>>(
      pos, rgb, opac, quat, scl, w2cr, w2ct, pa, pb, pc, n);
  render_k<<<NT, BT, 0, stream>>>(pa, pb, pc, out, n);
}

// Round 6
// 24.990 us; speedup vs baseline: 2.6858x; 1.0581x over previous
//
#include <hip/hip_runtime.h>
#include <math.h>

namespace {
constexpr int W = 256, H = 256, TILE = 16, NTX = 16, NT = 256, K = 256;
constexpr float FX = 200.0f, FY = 200.0f, NEARP = 0.3f, MAGIC = 1.2f;
constexpr float LP = 0.3f / (FX * FX);
constexpr float HALF_W = W * MAGIC / 2.0f / FX;   // 0.768
constexpr float HALF_H = H * MAGIC / 2.0f / FY;   // 0.768
constexpr float THDIAG = 0.05656854249492381f;    // 0.5*sqrt((TILE/FX)^2+(TILE/FY)^2)
constexpr int CAP = 2048;
constexpr int N_PAD = 10240;
constexpr int BT = 1024;                          // render block threads
constexpr int NB_MAX = 64;                        // max bin blocks (n <= 16384)
constexpr int SEG = 256;                          // per-(tile,block) segment cap
// ws layout
constexpr size_t A_OFF  = 0;                                   // pa: (mx,my,radius,z)
constexpr size_t B_OFF  = A_OFF + (size_t)N_PAD * 16;          // pb: (a,b,c,1/det)
constexpr size_t C_OFF  = B_OFF + (size_t)N_PAD * 16;          // pc: (opa,cr,cg,cb)
constexpr size_t SL_OFF = C_OFF + (size_t)N_PAD * 16;          // seglen[NT*NB_MAX]
constexpr size_t LD_OFF = SL_OFF + (size_t)NT * NB_MAX * 4;    // listd (dist<<32|g)
constexpr size_t LZ_OFF = LD_OFF + (size_t)NT * NB_MAX * SEG * 8;  // listz (z<<32|g)
constexpr size_t WS_FULL = LZ_OFF + (size_t)NT * NB_MAX * SEG * 8; // ~65 MB
}

struct Pre { float mx, my, z, a, b, c, radius; };

__device__ inline Pre preprocess(int g, const float* __restrict__ pos,
                                 const float* __restrict__ quat,
                                 const float* __restrict__ scl,
                                 const float* __restrict__ w2cr,
                                 const float* __restrict__ w2ct) {
  float p0 = pos[3*g+0], p1 = pos[3*g+1], p2 = pos[3*g+2];
  float qw = quat[4*g+0], qx = quat[4*g+1], qy = quat[4*g+2], qz = quat[4*g+3];
  float inv = 1.0f / sqrtf(qw*qw + qx*qx + qy*qy + qz*qz);
  qw *= inv; qx *= inv; qy *= inv; qz *= inv;
  float r00 = 1.f-2.f*(qy*qy+qz*qz), r01 = 2.f*(qx*qy-qw*qz), r02 = 2.f*(qx*qz+qw*qy);
  float r10 = 2.f*(qx*qy+qw*qz), r11 = 1.f-2.f*(qx*qx+qz*qz), r12 = 2.f*(qy*qz-qw*qx);
  float r20 = 2.f*(qx*qz-qw*qy), r21 = 2.f*(qy*qz+qw*qx), r22 = 1.f-2.f*(qx*qx+qy*qy);
  float e0 = expf(scl[3*g+0]); float s0 = e0*e0;
  float e1 = expf(scl[3*g+1]); float s1 = e1*e1;
  float e2 = expf(scl[3*g+2]); float s2 = e2*e2;
  float C00 = r00*r00*s0 + r01*r01*s1 + r02*r02*s2;
  float C01 = r00*r10*s0 + r01*r11*s1 + r02*r12*s2;
  float C02 = r00*r20*s0 + r01*r21*s1 + r02*r22*s2;
  float C11 = r10*r10*s0 + r11*r11*s1 + r12*r12*s2;
  float C12 = r10*r20*s0 + r11*r21*s1 + r12*r22*s2;
  float C22 = r20*r20*s0 + r21*r21*s1 + r22*r22*s2;
  float w00=w2cr[0],w01=w2cr[1],w02=w2cr[2];
  float w10=w2cr[3],w11=w2cr[4],w12=w2cr[5];
  float w20=w2cr[6],w21=w2cr[7],w22=w2cr[8];
  float x = w00*p0 + w01*p1 + w02*p2 + w2ct[0];
  float y = w10*p0 + w11*p1 + w12*p2 + w2ct[1];
  float z = w20*p0 + w21*p1 + w22*p2 + w2ct[2];
  float m00 = w00*C00 + w01*C01 + w02*C02;
  float m01 = w00*C01 + w01*C11 + w02*C12;
  float m02 = w00*C02 + w01*C12 + w02*C22;
  float m10 = w10*C00 + w11*C01 + w12*C02;
  float m11 = w10*C01 + w11*C11 + w12*C12;
  float m12 = w10*C02 + w11*C12 + w12*C22;
  float m20 = w20*C00 + w21*C01 + w22*C02;
  float m21 = w20*C01 + w21*C11 + w22*C12;
  float m22 = w20*C02 + w21*C12 + w22*C22;
  float v00 = m00*w00 + m01*w01 + m02*w02;
  float v01 = m00*w10 + m01*w11 + m02*w12;
  float v02 = m00*w20 + m01*w21 + m02*w22;
  float v10 = m10*w00 + m11*w01 + m12*w02;
  float v11 = m10*w10 + m11*w11 + m12*w12;
  float v12 = m10*w20 + m11*w21 + m12*w22;
  float v20 = m20*w00 + m21*w01 + m22*w02;
  float v21 = m20*w10 + m21*w11 + m22*w12;
  float v22 = m20*w20 + m21*w21 + m22*w22;
  float zc = fmaxf(z, 1e-6f);
  float iz = 1.0f / zc;
  float mx = x * iz, my = y * iz;
  float iz2 = iz * iz;
  float jx = -x * iz2, jy = -y * iz2;
  float a00 = iz*v00 + jx*v20, a01 = iz*v01 + jx*v21, a02 = iz*v02 + jx*v22;
  float a10 = iz*v10 + jy*v20, a11 = iz*v11 + jy*v21, a12 = iz*v12 + jy*v22;
  float A  = a00*iz + a02*jx + LP;
  float Bv = a01*iz + a02*jy;
  float Cv = a11*iz + a12*jy + LP;
  float mid = 0.5f*(A + Cv);
  float hh  = 0.5f*(A - Cv);
  float disc = fmaxf(hh*hh + Bv*Bv, 0.0f);
  float smax = sqrtf(fmaxf(mid + sqrtf(disc), 1e-12f));
  bool infr = (z > NEARP) && (fabsf(mx) < HALF_W) && (fabsf(my) < HALF_H);
  Pre r;
  r.mx = mx; r.my = my; r.z = z; r.a = A; r.b = Bv; r.c = Cv;
  r.radius = infr ? (3.0f * smax + THDIAG) : -1.0f;
  return r;
}

// ---- preprocess + segmented binning (LDS counters; no global atomics) ----

template <bool BIN>
__global__ __launch_bounds__(256)
void pre_bin(const float* __restrict__ pos, const float* __restrict__ rgb,
             const float* __restrict__ opac, const float* __restrict__ quat,
             const float* __restrict__ scl, const float* __restrict__ w2cr,
             const float* __restrict__ w2ct,
             float4* __restrict__ pa, float4* __restrict__ pb,
             float4* __restrict__ pc, int* __restrict__ seglen,
             unsigned long long* __restrict__ listd,
             unsigned long long* __restrict__ listz, int n) {
  __shared__ int s_tc[NT];
  const int tid = (int)threadIdx.x;
  const int blk = (int)blockIdx.x;
  if (BIN) {
    if (tid < NT) s_tc[tid] = 0;
    __syncthreads();
  }
  const int g = blk * 256 + tid;
  if (g < n) {
    Pre p = preprocess(g, pos, quat, scl, w2cr, w2ct);
    float det = fmaxf(p.a * p.c - p.b * p.b, 1e-12f);
    pa[g] = make_float4(p.mx, p.my, p.radius, p.z);
    pb[g] = make_float4(p.a, p.b, p.c, 1.0f / det);
    pc[g] = make_float4(1.0f / (1.0f + __expf(-opac[g])),
                        1.0f / (1.0f + __expf(-rgb[3*g+0])),
                        1.0f / (1.0f + __expf(-rgb[3*g+1])),
                        1.0f / (1.0f + __expf(-rgb[3*g+2])));
    if (BIN && p.radius >= 0.0f) {
      float r = p.radius;
      // tile center cx(tx) = (tx*16 + 8 - 128)/FX; conservative bbox + exact test
      int txlo = max(0,     (int)floorf(((p.mx - r) * FX + 120.0f) * 0.0625f));
      int txhi = min(NTX-1, (int)ceilf (((p.mx + r) * FX + 120.0f) * 0.0625f));
      int tylo = max(0,     (int)floorf(((p.my - r) * FY + 120.0f) * 0.0625f));
      int tyhi = min(NTX-1, (int)ceilf (((p.my + r) * FY + 120.0f) * 0.0625f));
      unsigned long long gbits = (unsigned int)g;
      for (int ty = tylo; ty <= tyhi; ++ty) {
        float cy = (ty * TILE + TILE * 0.5f - H * 0.5f) / FY;
        float ddy = cy - p.my;
        for (int tx = txlo; tx <= txhi; ++tx) {
          float cx = (tx * TILE + TILE * 0.5f - W * 0.5f) / FX;
          float ddx = cx - p.mx;
          float dist = sqrtf(ddx * ddx + ddy * ddy);   // exact reference predicate
          if (dist <= r) {
            int t = ty * NTX + tx;
            int slot = atomicAdd(&s_tc[t], 1);     // < 256 gaussians/block => slot < SEG
            size_t idx = ((size_t)t * NB_MAX + blk) * SEG + slot;
            listd[idx] = ((unsigned long long)__float_as_uint(dist) << 32) | gbits;
            listz[idx] = ((unsigned long long)__float_as_uint(p.z)  << 32) | gbits;
          }
        }
      }
    }
  }
  if (BIN) {
    __syncthreads();
    if (tid < NT) seglen[(size_t)tid * NB_MAX + blk] = s_tc[tid];  // block owns column
  }
}

// ------- hybrid bitonic, 1024 threads, S elems/thread, runtime M (pow2) -------
// Used only on the rare cnt>K path.

template <int S>
__device__ inline void hsortN(unsigned long long* key, int M) {
  const int tid = (int)threadIdx.x;
  __syncthreads();
  unsigned long long e[S];
  #pragma unroll
  for (int s = 0; s < S; ++s) {
    int i = tid + (s << 10);
    e[s] = (i < M) ? key[i] : ~0ull;
  }
  for (int k = 2; k <= M; k <<= 1) {
    for (int j = k >> 1; j >= 64; j >>= 1) {
      __syncthreads();
      #pragma unroll
      for (int s = 0; s < S; ++s) {
        int i = tid + (s << 10);
        if (i < M) key[i] = e[s];
      }
      __syncthreads();
      #pragma unroll
      for (int s = 0; s < S; ++s) {
        int i = tid + (s << 10);
        if (i < M) {
          unsigned long long p = key[i ^ j];
          bool takeMin = (((i & j) == 0) == ((i & k) == 0));
          e[s] = ((p < e[s]) == takeMin) ? p : e[s];   // keys unique
        }
      }
    }
    int j0 = ((k >> 1) < 32) ? (k >> 1) : 32;
    for (int j = j0; j >= 1; j >>= 1) {
      #pragma unroll
      for (int s = 0; s < S; ++s) {
        int i = tid + (s << 10);
        unsigned long long p = __shfl_xor(e[s], j, 64);
        bool takeMin = (((i & j) == 0) == ((i & k) == 0));
        e[s] = ((p < e[s]) == takeMin) ? p : e[s];
      }
    }
  }
  __syncthreads();
  #pragma unroll
  for (int s = 0; s < S; ++s) {
    int i = tid + (s << 10);
    if (i < M) key[i] = e[s];
  }
  __syncthreads();
}

// ---- shared tail: rank z-sort -> scatter -> split-k blend -> combine ----

__device__ inline void sort_blend_store(
    const float4* __restrict__ pa, const float4* __restrict__ pb,
    const float4* __restrict__ pc, float* __restrict__ out,
    unsigned long long* s_zkey, int* s_rank,
    float4* s_p0, float4* s_p1, float2* s_p2, float4* s_part,
    int cnt2, int tx, int ty) {
  const int tid = (int)threadIdx.x;
  // rank sort by (z, idx): 4 quarters of compares per element
  {
    const int e = tid & 255;
    const int q = tid >> 8;
    if (e < cnt2) {
      unsigned long long mykey = s_zkey[e];
      int jlo = q * 64;
      int jhi = min(cnt2, jlo + 64);
      int partial = 0;
      for (int j = jlo; j < jhi; ++j)
        partial += (s_zkey[j] < mykey) ? 1 : 0;   // keys unique
      if (partial) atomicAdd(&s_rank[e], partial);
    }
  }
  __syncthreads();
  if (tid < cnt2) {
    int g = (int)(s_zkey[tid] & 0xffffffffu);
    int r = s_rank[tid];
    float4 A = pa[g], B = pb[g], C = pc[g];
    s_p0[r] = make_float4(A.x, A.y, B.x, B.y);
    s_p1[r] = make_float4(B.z, B.w, C.x, C.y);
    s_p2[r] = make_float2(C.z, C.w);
  }
  __syncthreads();
  const int p    = tid & 255;
  const int q    = tid >> 8;
  const int prow = p / TILE, pcol = p % TILE;
  const float u = ((float)(tx * TILE + pcol) + 0.5f - W * 0.5f) / FX;
  const float v = ((float)(ty * TILE + prow) + 0.5f - H * 0.5f) / FY;
  const int chunk = (cnt2 + 3) >> 2;
  const int k0 = q * chunk;
  const int k1 = min(cnt2, k0 + chunk);
  float T = 1.0f, accr = 0.0f, accg = 0.0f, accb = 0.0f;
  for (int k2 = k0; k2 < k1; ++k2) {
    float4 p0 = s_p0[k2];
    float4 p1 = s_p1[k2];
    float2 p2 = s_p2[k2];
    float dx = u - p0.x;
    float dy = v - p0.y;
    float maha = (p1.x*dx*dx - 2.0f*p0.w*dx*dy + p0.z*dy*dy) * p1.y;
    float alpha = fminf(p1.z * __expf(-0.5f * maha), 0.99f);
    float w = alpha * T;
    accr += w * p1.w;
    accg += w * p2.x;
    accb += w * p2.y;
    T *= (1.0f - alpha);
  }
  s_part[tid] = make_float4(accr, accg, accb, T);
  __syncthreads();
  if (q == 0) {
    float4 P0 = s_part[p];
    float4 P1 = s_part[p + 256];
    float4 P2 = s_part[p + 512];
    float4 P3 = s_part[p + 768];
    float r = P0.x + P0.w * (P1.x + P1.w * (P2.x + P2.w * P3.x));
    float g = P0.y + P0.w * (P1.y + P1.w * (P2.y + P2.w * P3.y));
    float b = P0.z + P0.w * (P1.z + P1.w * (P2.z + P2.w * P3.z));
    const int row = ty * TILE + prow;
    const int col = tx * TILE + pcol;
    const int o = (row * W + col) * 3;
    out[o+0] = fminf(fmaxf(r, 0.0f), 1.0f);
    out[o+1] = fminf(fmaxf(g, 0.0f), 1.0f);
    out[o+2] = fminf(fmaxf(b, 0.0f), 1.0f);
  }
}

// ---- render from prebuilt segmented lists ----

__global__ __launch_bounds__(BT)
void render_list(const float4* __restrict__ pa, const float4* __restrict__ pb,
                 const float4* __restrict__ pc, const int* __restrict__ seglen,
                 const unsigned long long* __restrict__ listd,
                 const unsigned long long* __restrict__ listz,
                 float* __restrict__ out, int nb) {
  __shared__ unsigned long long s_dkey[CAP];
  __shared__ unsigned long long s_zkey[CAP];
  __shared__ int s_off[NB_MAX + 1];
  __shared__ int s_rank[K];
  __shared__ float4 s_p0[K];
  __shared__ float4 s_p1[K];
  __shared__ float2 s_p2[K];
  __shared__ float4 s_part[BT];

  const int t  = (int)blockIdx.x;
  const int tx = t % NTX;
  const int ty = t / NTX;
  const int tid = (int)threadIdx.x;

  if (tid < K) s_rank[tid] = 0;
  if (tid < 64) {
    int v = (tid < nb) ? seglen[(size_t)t * NB_MAX + tid] : 0;
    #pragma unroll
    for (int d = 1; d < 64; d <<= 1) {
      int u2 = __shfl_up(v, d, 64);
      if (tid >= d) v += u2;
    }
    if (tid == 0) s_off[0] = 0;
    if (tid < nb) s_off[tid + 1] = v;
  }
  __syncthreads();
  int cnt = min(s_off[nb], CAP);

  // gather segments into contiguous LDS (binary search over prefix)
  for (int i = tid; i < cnt; i += BT) {
    int lo = 0, hi = nb;
    while (hi - lo > 1) {
      int mid = (lo + hi) >> 1;
      if (s_off[mid] <= i) lo = mid; else hi = mid;
    }
    size_t src = ((size_t)t * NB_MAX + lo) * SEG + (size_t)(i - s_off[lo]);
    s_dkey[i] = listd[src];
    s_zkey[i] = listz[src];
  }
  __syncthreads();
  int cnt2 = cnt;

  if (cnt > K) {
    // rare: exact top-K by (dist, idx) ascending == top_k on -dist
    int M = 512; while (M < cnt) M <<= 1;
    for (int i = cnt + tid; i < M; i += BT) s_dkey[i] = ~0ull;
    if (M <= 1024) hsortN<1>(s_dkey, M);
    else           hsortN<2>(s_dkey, 2048);
    if (tid < K) {
      int g = (int)(s_dkey[tid] & 0xffffffffu);
      s_zkey[tid] = ((unsigned long long)__float_as_uint(pa[g].w) << 32) |
                    (unsigned int)g;
    }
    __syncthreads();
    cnt2 = K;
  }

  sort_blend_store(pa, pb, pc, out, s_zkey, s_rank, s_p0, s_p1, s_p2, s_part,
                   cnt2, tx, ty);
}

// ---- fallback: round-5 scan render (used only if ws too small) ----

__global__ __launch_bounds__(BT)
void render_scan(const float4* __restrict__ pa, const float4* __restrict__ pb,
                 const float4* __restrict__ pc, float* __restrict__ out, int n) {
  __shared__ unsigned long long s_dkey[CAP];
  __shared__ unsigned long long s_zkey[CAP];
  __shared__ int s_rank[K];
  __shared__ float4 s_p0[K];
  __shared__ float4 s_p1[K];
  __shared__ float2 s_p2[K];
  __shared__ float4 s_part[BT];
  __shared__ int s_cnt;

  const int t  = (int)blockIdx.x;
  const int tx = t % NTX;
  const int ty = t / NTX;
  const int tid = (int)threadIdx.x;
  const int lane = tid & 63;
  const float cxc = (tx * TILE + TILE * 0.5f - W * 0.5f) / FX;
  const float cyc = (ty * TILE + TILE * 0.5f - H * 0.5f) / FY;

  if (tid == 0) s_cnt = 0;
  if (tid < K) s_rank[tid] = 0;
  __syncthreads();

  for (int g = tid; g < n; g += BT) {
    float4 v = pa[g];
    float ddx = cxc - v.x, ddy = cyc - v.y;
    float dist = sqrtf(ddx * ddx + ddy * ddy);
    bool hit = (v.z >= 0.0f) && (dist <= v.z);
    unsigned long long m = __ballot(hit);
    if (m) {
      int leader = __ffsll((long long)m) - 1;
      int base = 0;
      if (lane == leader) base = atomicAdd(&s_cnt, __popcll(m));
      base = __shfl(base, leader, 64);
      if (hit) {
        int slot = base + __popcll(m & ((1ull << lane) - 1ull));
        if (slot < CAP) {
          s_dkey[slot] = ((unsigned long long)__float_as_uint(dist) << 32) |
                         (unsigned int)g;
          s_zkey[slot] = ((unsigned long long)__float_as_uint(v.w) << 32) |
                         (unsigned int)g;
        }
      }
    }
  }
  __syncthreads();
  int cnt = min(s_cnt, CAP);
  int cnt2 = cnt;

  if (cnt > K) {
    int M = 512; while (M < cnt) M <<= 1;
    for (int i = cnt + tid; i < M; i += BT) s_dkey[i] = ~0ull;
    if (M <= 1024) hsortN<1>(s_dkey, M);
    else           hsortN<2>(s_dkey, 2048);
    if (tid < K) {
      int g = (int)(s_dkey[tid] & 0xffffffffu);
      s_zkey[tid] = ((unsigned long long)__float_as_uint(pa[g].w) << 32) |
                    (unsigned int)g;
    }
    __syncthreads();
    cnt2 = K;
  }

  sort_blend_store(pa, pb, pc, out, s_zkey, s_rank, s_p0, s_p1, s_p2, s_part,
                   cnt2, tx, ty);
}

extern "C" void kernel_launch(void* const* d_in, const int* in_sizes, int n_in,
                              void* d_out, int out_size, void* d_ws, size_t ws_size,
                              hipStream_t stream) {
  const float* pos  = (const float*)d_in[0];
  const float* rgb  = (const float*)d_in[1];
  const float* opac = (const float*)d_in[2];
  const float* quat = (const float*)d_in[3];
  const float* scl  = (const float*)d_in[4];
  const float* w2cr = (const float*)d_in[5];
  const float* w2ct = (const float*)d_in[6];
  float* out = (float*)d_out;
  const int n = in_sizes[0] / 3;
  const int nb = (n + 255) / 256;

  char* ws = (char*)d_ws;
  float4* pa = (float4*)(ws + A_OFF);
  float4* pb = (float4*)(ws + B_OFF);
  float4* pc = (float4*)(ws + C_OFF);
  int* seglen = (int*)(ws + SL_OFF);
  unsigned long long* listd = (unsigned long long*)(ws + LD_OFF);
  unsigned long long* listz = (unsigned long long*)(ws + LZ_OFF);

  if (ws_size >= WS_FULL && nb <= NB_MAX) {
    pre_bin<true><<<nb, 256, 0, stream>>>(
        pos, rgb, opac, quat, scl, w2cr, w2ct, pa, pb, pc, seglen, listd, listz, n);
    render_list<<<NT, BT, 0, stream>>>(pa, pb, pc, seglen, listd, listz, out, nb);
  } else {
    pre_bin<false><<<nb, 256, 0, stream>>>(
        pos, rgb, opac, quat, scl, w2cr, w2ct, pa, pb, pc, seglen, listd, listz, n);
    render_scan<<<NT, BT, 0, stream>>>(pa, pb, pc, out, n);
  }
}